// Round 6
// baseline (815.301 us; speedup 1.0000x reference)
//
#include <hip/hip_runtime.h>
#include <math.h>

// Problem constants
#define DM    512
#define DI    1024
#define DSN   16
#define DTR   32
#define DFFN  2048
#define BB    8
#define SS    512
#define TTM   1024
#define LCAT  1536
#define NC    32      // scan chunks per sequence

#define ACT_NONE     0
#define ACT_RELU     1
#define ACT_DELTA    3   // split epilogue: n<1024 softplus+bias -> Cb(delta bf16); 1024<=n<1056 -> C2(bc fp32)

typedef __attribute__((ext_vector_type(8))) short short8;
typedef __attribute__((ext_vector_type(4))) float f32x4;

__device__ __forceinline__ unsigned short f2b(float f) {
    unsigned int u = __float_as_uint(f);
    return (unsigned short)((u + 0x7FFFu + ((u >> 16) & 1u)) >> 16);
}
__device__ __forceinline__ float b2f(unsigned short h) {
    return __uint_as_float(((unsigned int)h) << 16);
}
__device__ __forceinline__ float fast_softplus(float v) {
    return (v > 20.f) ? v : __logf(1.f + __expf(v));
}
__device__ __forceinline__ void gld16(const void* g, void* l) {
    __builtin_amdgcn_global_load_lds(
        (const __attribute__((address_space(1))) void*)g,
        (__attribute__((address_space(3))) void*)l, 16, 0, 0);
}

__device__ __forceinline__ int map_row(int m, int mb, int bs, int ro) {
    int q = m / mb;
    return q * bs + ro + (m - q * mb);
}

// ================= bf16 MFMA GEMM: C[m,n] = act(A[row(m),k] * W[n,k] + bias[n])
// A: bf16, row stride K. W: bf16, N x K row-major. Tile 128x128, BK=32.
// LDS is stored in MFMA-FRAGMENT ORDER: chunk c (16B) = [wy*256 + i*64 + g*16 + fm]
// holds A[wy*64+i*16+fm][k0+g*8 .. +8]. The staging gld16 gathers per-lane global
// addresses into contiguous LDS (base + lane*16B), and fragment ds_read_b128 is
// base + lane*16B -> contiguous, conflict-free (2 lanes/bank).
__global__ __launch_bounds__(256) void mgemm_kernel(
    const unsigned short* __restrict__ A, int mb, int bs, int ro,
    const unsigned short* __restrict__ W, const float* __restrict__ bias,
    float* __restrict__ Cf, unsigned short* __restrict__ Cb,
    float* __restrict__ C2,
    int N, int K, int act)
{
    __shared__ __align__(16) unsigned short As[128 * 32];
    __shared__ __align__(16) unsigned short Bs[128 * 32];
    int tid = threadIdx.x;
    int lane = tid & 63, wave = tid >> 6;
    int wy = wave >> 1, wx = wave & 1;
    // XCD-band swizzle (gridDim.y assumed divisible by 8)
    int nx = gridDim.x;
    int f = blockIdx.y * nx + blockIdx.x;
    int xcd = f & 7, j2 = f >> 3;
    int bandh = gridDim.y >> 3;
    int m0 = (xcd * bandh + j2 / nx) * 128;
    int n0 = (j2 % nx) * 128;

    // staging pointers: wave stages chunks c = wave*128 + j*64 + lane (j=0,1)
    const unsigned short* ga[2];
    const unsigned short* gb[2];
    unsigned short* la[2];
    unsigned short* lb[2];
    #pragma unroll
    for (int j = 0; j < 2; j++) {
        int c  = wave * 128 + j * 64 + lane;
        int cy = c >> 8;            // which 64-row half (matches wy on read side)
        int rem = c & 255;
        int ci = rem >> 6;          // fragment i
        int cg = (rem >> 4) & 3;    // k-chunk g
        int cf = rem & 15;          // row within 16
        int arow = map_row(m0 + cy * 64 + ci * 16 + cf, mb, bs, ro);
        ga[j] = A + (size_t)arow * K + cg * 8;
        gb[j] = W + (size_t)(n0 + cy * 64 + ci * 16 + cf) * K + cg * 8;
        la[j] = As + (size_t)(wave * 128 + j * 64) * 8;   // chunk*8 shorts
        lb[j] = Bs + (size_t)(wave * 128 + j * 64) * 8;
    }
    const unsigned short* arp = As + (size_t)wy * 256 * 8 + lane * 8;
    const unsigned short* brp = Bs + (size_t)wx * 256 * 8 + lane * 8;

    f32x4 acc[4][4];
    #pragma unroll
    for (int i = 0; i < 4; i++)
        #pragma unroll
        for (int j = 0; j < 4; j++) acc[i][j] = 0.f;

    for (int k0 = 0; k0 < K; k0 += 32) {
        #pragma unroll
        for (int j = 0; j < 2; j++) {
            gld16(ga[j] + k0, la[j]);
            gld16(gb[j] + k0, lb[j]);
        }
        __syncthreads();
        short8 af[4], bfr[4];
        #pragma unroll
        for (int t = 0; t < 4; t++) af[t]  = *(const short8*)(arp + t * 512);
        #pragma unroll
        for (int t = 0; t < 4; t++) bfr[t] = *(const short8*)(brp + t * 512);
        #pragma unroll
        for (int i = 0; i < 4; i++)
            #pragma unroll
            for (int j = 0; j < 4; j++)
                acc[i][j] = __builtin_amdgcn_mfma_f32_16x16x32_bf16(af[i], bfr[j], acc[i][j], 0, 0, 0);
        __syncthreads();
    }

    // epilogue: C/D layout col=lane&15 (n), row=(lane>>4)*4+reg (m)
    int en = lane & 15, em = (lane >> 4) * 4;
    if (act == ACT_DELTA) {
        #pragma unroll
        for (int j = 0; j < 4; j++) {
            int n = n0 + wx * 64 + j * 16 + en;
            bool is_delta = (n < 1024);
            if (!is_delta && n >= 1056) continue;
            float bv = is_delta ? bias[n] : 0.f;
            #pragma unroll
            for (int i = 0; i < 4; i++) {
                int mbase = m0 + wy * 64 + i * 16 + em;
                #pragma unroll
                for (int r = 0; r < 4; r++) {
                    float v = acc[i][j][r] + bv;
                    if (is_delta) {
                        Cb[(size_t)(mbase + r) * 1024 + n] = f2b(fast_softplus(v));
                    } else {
                        C2[(size_t)(mbase + r) * 32 + (n - 1024)] = v;
                    }
                }
            }
        }
        return;
    }
    #pragma unroll
    for (int j = 0; j < 4; j++) {
        int n = n0 + wx * 64 + j * 16 + en;
        float bv = bias ? bias[n] : 0.f;
        #pragma unroll
        for (int i = 0; i < 4; i++) {
            int mbase = m0 + wy * 64 + i * 16 + em;
            #pragma unroll
            for (int r = 0; r < 4; r++) {
                float v = acc[i][j][r] + bv;
                if (act == ACT_RELU) v = v > 0.f ? v : 0.f;
                size_t off = (size_t)(mbase + r) * N + n;
                if (Cb) Cb[off] = f2b(v);
                else    Cf[off] = v;
            }
        }
    }
}

// ================= Wcomb fill: rows 0..1023 = dt_w @ xproj[:32]; 1024..1055 = xproj rows 32..63; rest 0
__global__ void wcomb_kernel(const float* __restrict__ dt_w,
                             const float* __restrict__ xproj,
                             unsigned short* __restrict__ out)
{
    int idx = blockIdx.x * 256 + threadIdx.x;   // n*1024 + k, n < 1152
    int n = idx >> 10, k = idx & 1023;
    float v = 0.f;
    if (n < 1024) {
        #pragma unroll
        for (int r = 0; r < DTR; r++)
            v = fmaf(dt_w[n * DTR + r], xproj[r * 1024 + k], v);
    } else if (n < 1056) {
        v = xproj[(n - 1024 + 32) * 1024 + k];
    }
    out[idx] = f2b(v);
}

// ================= Depthwise causal conv (width 4) + bias + SiLU. bf16 in, bf16 out.
__global__ void conv_silu_kernel(const unsigned short* __restrict__ xz,
                                 const float* __restrict__ cw,
                                 const float* __restrict__ cb,
                                 unsigned short* __restrict__ xc, int L, int total)
{
    int idx = blockIdx.x * blockDim.x + threadIdx.x;
    if (idx >= total) return;
    int d = idx & (DI - 1);
    int r = idx >> 10;     // b*L + l
    int l = r % L;
    float acc = cb[d];
    #pragma unroll
    for (int k = 0; k < 4; k++) {
        int ls = l - 3 + k;
        if (ls >= 0) acc = fmaf(b2f(xz[(size_t)(r - 3 + k) * 2048 + d]), cw[d * 4 + k], acc);
    }
    float s = acc / (1.f + __expf(-acc));
    xc[idx] = f2b(s);
}

// ================= Chunked selective scan (delta bf16)
__global__ __launch_bounds__(256) void scan_part1(
    const unsigned short* __restrict__ delta, const unsigned short* __restrict__ xc,
    const float* __restrict__ bc, const float* __restrict__ A_log,
    float* __restrict__ part_h, float* __restrict__ part_s, int L, int CH)
{
    int tid = threadIdx.x;
    int dblk = blockIdx.x & 3;
    int c    = (blockIdx.x >> 2) & (NC - 1);
    int b    = blockIdx.x >> 7;
    int d    = dblk * 256 + tid;
    float A[DSN];
    #pragma unroll
    for (int s = 0; s < DSN; s++) A[s] = -__expf(A_log[d * DSN + s]);
    float h[DSN];
    #pragma unroll
    for (int s = 0; s < DSN; s++) h[s] = 0.f;
    float ssum = 0.f;
    int l0 = c * CH;
    for (int l = l0; l < l0 + CH; l++) {
        size_t r = (size_t)b * L + l;
        float4 bq[4];
        const float4* bp = (const float4*)(bc + r * 32);
        #pragma unroll
        for (int q = 0; q < 4; q++) bq[q] = bp[q];
        const float* Bm = (const float*)&bq[0];
        float dl = b2f(delta[r * DI + d]);
        float u  = b2f(xc[r * DI + d]);
        float du = dl * u;
        ssum += dl;
        #pragma unroll
        for (int s = 0; s < DSN; s++)
            h[s] = fmaf(__expf(dl * A[s]), h[s], du * Bm[s]);
    }
    size_t base = ((size_t)(b * NC + c) * DI + d) * DSN;
    #pragma unroll
    for (int q = 0; q < 4; q++)
        ((float4*)(part_h + base))[q] = make_float4(h[q*4], h[q*4+1], h[q*4+2], h[q*4+3]);
    part_s[(size_t)(b * NC + c) * DI + d] = ssum;
}

__global__ __launch_bounds__(256) void scan_combine(
    const float* __restrict__ A_log,
    float* __restrict__ part_h, const float* __restrict__ part_s)
{
    int idx = blockIdx.x * 256 + threadIdx.x;
    int b = idx >> 10, d = idx & (DI - 1);
    float A[DSN];
    #pragma unroll
    for (int s = 0; s < DSN; s++) A[s] = -__expf(A_log[d * DSN + s]);
    float h[DSN];
    #pragma unroll
    for (int s = 0; s < DSN; s++) h[s] = 0.f;
    for (int c = 0; c < NC; c++) {
        size_t base = ((size_t)(b * NC + c) * DI + d) * DSN;
        float4 ph4[4];
        #pragma unroll
        for (int q = 0; q < 4; q++) ph4[q] = ((const float4*)(part_h + base))[q];
        const float* ph = (const float*)&ph4[0];
        float S = part_s[(size_t)(b * NC + c) * DI + d];
        #pragma unroll
        for (int q = 0; q < 4; q++)
            ((float4*)(part_h + base))[q] = make_float4(h[q*4], h[q*4+1], h[q*4+2], h[q*4+3]);
        #pragma unroll
        for (int s = 0; s < DSN; s++)
            h[s] = fmaf(__expf(A[s] * S), h[s], ph[s]);
    }
}

// pass 3: rescan chunk from h_in, emit gated output to bf16 buffer.
__global__ __launch_bounds__(256) void scan_part2(
    const unsigned short* __restrict__ delta, const unsigned short* __restrict__ xc,
    const float* __restrict__ bc, const unsigned short* __restrict__ xz,
    const float* __restrict__ A_log, const float* __restrict__ Dv,
    const float* __restrict__ part_h,
    unsigned short* __restrict__ out, int L, int CH)
{
    int tid = threadIdx.x;
    int dblk = blockIdx.x & 3;
    int c    = (blockIdx.x >> 2) & (NC - 1);
    int b    = blockIdx.x >> 7;
    int d    = dblk * 256 + tid;
    float A[DSN];
    #pragma unroll
    for (int s = 0; s < DSN; s++) A[s] = -__expf(A_log[d * DSN + s]);
    float Dvd = Dv[d];
    size_t base = ((size_t)(b * NC + c) * DI + d) * DSN;
    float h4[4][4];
    #pragma unroll
    for (int q = 0; q < 4; q++) *((float4*)h4[q]) = ((const float4*)(part_h + base))[q];
    float h[DSN];
    #pragma unroll
    for (int s = 0; s < DSN; s++) h[s] = h4[s >> 2][s & 3];
    int l0 = c * CH;
    for (int l = l0; l < l0 + CH; l++) {
        size_t r = (size_t)b * L + l;
        float4 bq[8];
        const float4* bp = (const float4*)(bc + r * 32);
        #pragma unroll
        for (int q = 0; q < 8; q++) bq[q] = bp[q];
        const float* Bm = (const float*)&bq[0];
        const float* Cm = Bm + DSN;
        float dl = b2f(delta[r * DI + d]);
        float u  = b2f(xc[r * DI + d]);
        float du = dl * u;
        float y = 0.f;
        #pragma unroll
        for (int s = 0; s < DSN; s++) {
            h[s] = fmaf(__expf(dl * A[s]), h[s], du * Bm[s]);
            y = fmaf(h[s], Cm[s], y);
        }
        float z = b2f(xz[r * 2048 + DI + d]);
        float sil = z / (1.f + __expf(-z));
        out[r * DI + d] = f2b((y + u * Dvd) * sil);
    }
}

// ================= residual add + LayerNorm; optional fp32 and bf16 outputs
__global__ __launch_bounds__(128) void addln_kernel(
    const float* __restrict__ a, int amb, int absd, int aro, int lda,
    const float* __restrict__ bsrc,
    const float* __restrict__ g, const float* __restrict__ be,
    float* __restrict__ outf, int omb, int obsd, int oro, int ldo,
    unsigned short* __restrict__ outb, int bmb, int bbsd, int bro, int ldb)
{
    int m = blockIdx.x, t = threadIdx.x;
    int ar = map_row(m, amb, absd, aro);
    float4 x4 = ((const float4*)(a + (size_t)ar * lda))[t];
    float4 y4 = ((const float4*)(bsrc + (size_t)m * DM))[t];
    float v[4] = {x4.x + y4.x, x4.y + y4.y, x4.z + y4.z, x4.w + y4.w};
    float sum = v[0] + v[1] + v[2] + v[3];
    float sq  = v[0]*v[0] + v[1]*v[1] + v[2]*v[2] + v[3]*v[3];
    #pragma unroll
    for (int o = 32; o > 0; o >>= 1) {
        sum += __shfl_down(sum, o);
        sq  += __shfl_down(sq, o);
    }
    __shared__ float s0[2], s1[2];
    if ((t & 63) == 0) { s0[t >> 6] = sum; s1[t >> 6] = sq; }
    __syncthreads();
    float tot = s0[0] + s0[1];
    float tsq = s1[0] + s1[1];
    float mu = tot * (1.f / DM);
    float var = tsq * (1.f / DM) - mu * mu;
    float rs = rsqrtf(var + 1e-6f);
    float4 g4 = ((const float4*)g)[t];
    float4 b4 = ((const float4*)be)[t];
    float o0 = (v[0] - mu) * rs * g4.x + b4.x;
    float o1 = (v[1] - mu) * rs * g4.y + b4.y;
    float o2 = (v[2] - mu) * rs * g4.z + b4.z;
    float o3 = (v[3] - mu) * rs * g4.w + b4.w;
    if (outf) {
        int orow = map_row(m, omb, obsd, oro);
        ((float4*)(outf + (size_t)orow * ldo))[t] = make_float4(o0, o1, o2, o3);
    }
    if (outb) {
        int brow = map_row(m, bmb, bbsd, bro);
        ((ushort4*)(outb + (size_t)brow * ldb))[t] =
            make_ushort4(f2b(o0), f2b(o1), f2b(o2), f2b(o3));
    }
}

// ================= fp32 -> bf16 convert (n4 float4 groups)
__global__ void f2b_kernel(const float* __restrict__ in, unsigned short* __restrict__ out, int n4)
{
    int i = blockIdx.x * 256 + threadIdx.x;
    if (i >= n4) return;
    float4 v = ((const float4*)in)[i];
    ((ushort4*)out)[i] = make_ushort4(f2b(v.x), f2b(v.y), f2b(v.z), f2b(v.w));
}

// ================= merged 6-weight fp32 -> bf16 convert (contiguous bf16 output region)
struct W6 { const float* p[6]; };
__global__ void wconv_kernel(W6 w, unsigned short* __restrict__ out)
{
    const int cum[7] = {0, 262144, 524288, 655360, 786432, 1048576, 1310720};
    int i = blockIdx.x * 256 + threadIdx.x;
    if (i >= 1310720) return;
    int seg = 0;
    #pragma unroll
    for (int s = 1; s < 6; s++) seg += (i >= cum[s]);
    float4 v = ((const float4*)w.p[seg])[i - cum[seg]];
    ((ushort4*)out)[i] = make_ushort4(f2b(v.x), f2b(v.y), f2b(v.z), f2b(v.w));
}

// ================= memory(fp32) -> catb(bf16) rows [b*1536 + 0..1023]
__global__ void mem2catb_kernel(const float* __restrict__ mem, unsigned short* __restrict__ catb)
{
    int f = blockIdx.x * blockDim.x + threadIdx.x;
    const int total = BB * TTM * DM / 4;
    if (f >= total) return;
    const int per_b = TTM * DM / 4;
    int b = f / per_b, rem = f - b * per_b;
    float4 v = ((const float4*)mem)[f];
    ((ushort4*)catb)[(size_t)b * (LCAT * DM / 4) + rem] =
        make_ushort4(f2b(v.x), f2b(v.y), f2b(v.z), f2b(v.w));
}

static void run_scan(const unsigned short* dltb, const unsigned short* xcb, const float* bc,
                     const unsigned short* xzb, const float* A_log, const float* Dv,
                     float* part_h, float* part_s, unsigned short* out, int L,
                     hipStream_t stream)
{
    int CH = L / NC;
    int blocks = BB * NC * (DI / 256);
    scan_part1<<<blocks, 256, 0, stream>>>(dltb, xcb, bc, A_log, part_h, part_s, L, CH);
    scan_combine<<<BB * DI / 256, 256, 0, stream>>>(A_log, part_h, part_s);
    scan_part2<<<blocks, 256, 0, stream>>>(dltb, xcb, bc, xzb, A_log, Dv, part_h, out, L, CH);
}

extern "C" void kernel_launch(void* const* d_in, const int* in_sizes, int n_in,
                              void* d_out, int out_size, void* d_ws, size_t ws_size,
                              hipStream_t stream)
{
    const float* tgt       = (const float*)d_in[0];
    const float* memory    = (const float*)d_in[1];
    const float* s_in_w    = (const float*)d_in[2];
    const float* s_conv_w  = (const float*)d_in[3];
    const float* s_conv_b  = (const float*)d_in[4];
    const float* s_xproj_w = (const float*)d_in[5];
    const float* s_dt_w    = (const float*)d_in[6];
    const float* s_dt_b    = (const float*)d_in[7];
    const float* s_A_log   = (const float*)d_in[8];
    const float* s_D_vec   = (const float*)d_in[9];
    const float* s_out_w   = (const float*)d_in[10];
    const float* c_in_w    = (const float*)d_in[11];
    const float* c_conv_w  = (const float*)d_in[12];
    const float* c_conv_b  = (const float*)d_in[13];
    const float* c_xproj_w = (const float*)d_in[14];
    const float* c_dt_w    = (const float*)d_in[15];
    const float* c_dt_b    = (const float*)d_in[16];
    const float* c_A_log   = (const float*)d_in[17];
    const float* c_D_vec   = (const float*)d_in[18];
    const float* c_out_w   = (const float*)d_in[19];
    const float* ln1_g     = (const float*)d_in[20];
    const float* ln1_b     = (const float*)d_in[21];
    const float* ln2_g     = (const float*)d_in[22];
    const float* ln2_b     = (const float*)d_in[23];
    const float* ln3_g     = (const float*)d_in[24];
    const float* ln3_b     = (const float*)d_in[25];
    const float* ffn_w1    = (const float*)d_in[26];
    const float* ffn_b1    = (const float*)d_in[27];
    const float* ffn_w2    = (const float*)d_in[28];
    const float* ffn_b2    = (const float*)d_in[29];
    float* outp = (float*)d_out;

    // ---- workspace layout ----
    // fp32 region (floats): 11,141,120 floats = 44.6 MB
    float* ws     = (float*)d_ws;
    float* bc     = ws;                     // 393216  (12288 x 32: B|C)
    float* proj   = bc     + 393216;        // 2097152
    float* t1     = proj   + 2097152;       // 2097152
    float* tbuf   = t1     + 2097152;       // 2097152
    float* part_h = tbuf   + 2097152;       // 4194304
    float* part_s = part_h + 4194304;       // 262144
    // bf16 region (ushorts): 81,002,496 elems = 162 MB ; total ~207 MB
    unsigned short* ub      = (unsigned short*)(part_s + 262144);
    unsigned short* dltb    = ub;                   // 12582912 (bf16 delta; ffnout aliases)
    unsigned short* catb    = dltb    + 12582912;   // 6291456
    unsigned short* tgtb    = catb    + 6291456;    // 2097152
    unsigned short* xzb     = tgtb    + 2097152;    // 25165824 (also fbuf alias)
    unsigned short* xcb     = xzb     + 25165824;   // 12582912
    unsigned short* ygb     = xcb     + 12582912;   // 12582912
    unsigned short* tbbf    = ygb     + 12582912;   // 2097152
    unsigned short* s_in_wb = tbbf    + 2097152;    // 1048576  (6-weight block, contiguous)
    unsigned short* c_in_wb = s_in_wb + 1048576;    // 1048576
    unsigned short* s_out_wb= c_in_wb + 1048576;    // 524288
    unsigned short* c_out_wb= s_out_wb+ 524288;     // 524288
    unsigned short* w1b     = c_out_wb+ 524288;     // 1048576
    unsigned short* w2b     = w1b     + 1048576;    // 1048576
    unsigned short* wcomb_s = w2b     + 1048576;    // 1179648 (1152 x 1024)
    unsigned short* wcomb_c = wcomb_s + 1179648;    // 1179648
    unsigned short* fbuf    = xzb;                  // FFN hidden alias
    float* ffnout = (float*)dltb;                   // alias (dltb dead after cross scan)

    // ---- converts & combined-weight fills ----
    f2b_kernel<<<(2097152/4 + 255)/256, 256, 0, stream>>>(tgt, tgtb, 2097152/4);
    mem2catb_kernel<<<(BB*TTM*DM/4 + 255)/256, 256, 0, stream>>>(memory, catb);
    {
        W6 w; w.p[0]=s_in_w; w.p[1]=c_in_w; w.p[2]=s_out_w; w.p[3]=c_out_w; w.p[4]=ffn_w1; w.p[5]=ffn_w2;
        wconv_kernel<<<(1310720 + 255)/256, 256, 0, stream>>>(w, s_in_wb);
    }
    wcomb_kernel<<<(1152*1024)/256, 256, 0, stream>>>(s_dt_w, s_xproj_w, wcomb_s);
    wcomb_kernel<<<(1152*1024)/256, 256, 0, stream>>>(c_dt_w, c_xproj_w, wcomb_c);

    // ---- self mamba (L=512, M=4096) ----
    mgemm_kernel<<<dim3(2048/128, 4096/128), 256, 0, stream>>>(
        tgtb, 4096, 0, 0, s_in_wb, nullptr, nullptr, xzb, nullptr, 2048, 512, ACT_NONE);
    conv_silu_kernel<<<(BB*SS*DI + 255)/256, 256, 0, stream>>>(xzb, s_conv_w, s_conv_b, xcb, SS, BB*SS*DI);
    // combined delta + BC GEMM: M=4096, Ncomb=1152, K=1024
    mgemm_kernel<<<dim3(1152/128, 4096/128), 256, 0, stream>>>(
        xcb, 4096, 0, 0, wcomb_s, s_dt_b, nullptr, dltb, bc, 1152, 1024, ACT_DELTA);
    run_scan(dltb, xcb, bc, xzb, s_A_log, s_D_vec, part_h, part_s, ygb, SS, stream);
    mgemm_kernel<<<dim3(512/128, 4096/128), 256, 0, stream>>>(
        ygb, 4096, 0, 0, s_out_wb, nullptr, proj, nullptr, nullptr, 512, 1024, ACT_NONE);
    // t = LN(tgt + proj): fp32 -> t1, bf16 -> catb rows [b*1536+1024+l]
    addln_kernel<<<4096, 128, 0, stream>>>(
        tgt, 4096, 0, 0, DM, proj, ln1_g, ln1_b,
        t1, 4096, 0, 0, DM, catb, 512, 1536, 1024, DM);

    // ---- cross mamba (L=1536, M=12288) ----
    mgemm_kernel<<<dim3(2048/128, 12288/128), 256, 0, stream>>>(
        catb, 12288, 0, 0, c_in_wb, nullptr, nullptr, xzb, nullptr, 2048, 512, ACT_NONE);
    conv_silu_kernel<<<(BB*LCAT*DI + 255)/256, 256, 0, stream>>>(xzb, c_conv_w, c_conv_b, xcb, LCAT, BB*LCAT*DI);
    mgemm_kernel<<<dim3(1152/128, 12288/128), 256, 0, stream>>>(
        xcb, 12288, 0, 0, wcomb_c, c_dt_b, nullptr, dltb, bc, 1152, 1024, ACT_DELTA);
    run_scan(dltb, xcb, bc, xzb, c_A_log, c_D_vec, part_h, part_s, ygb, LCAT, stream);
    // out proj over last S rows per batch: row(m) = (m/512)*1536 + 1024 + m%512
    mgemm_kernel<<<dim3(512/128, 4096/128), 256, 0, stream>>>(
        ygb, 512, 1536, 1024, c_out_wb, nullptr, proj, nullptr, nullptr, 512, 1024, ACT_NONE);
    addln_kernel<<<4096, 128, 0, stream>>>(
        t1, 4096, 0, 0, DM, proj, ln2_g, ln2_b,
        tbuf, 4096, 0, 0, DM, tbbf, 4096, 0, 0, DM);

    // ---- FFN ----
    mgemm_kernel<<<dim3(2048/128, 4096/128), 256, 0, stream>>>(
        tbbf, 4096, 0, 0, w1b, ffn_b1, nullptr, fbuf, nullptr, 2048, 512, ACT_RELU);
    mgemm_kernel<<<dim3(512/128, 4096/128), 256, 0, stream>>>(
        fbuf, 4096, 0, 0, w2b, ffn_b2, ffnout, nullptr, nullptr, 512, 2048, ACT_NONE);
    addln_kernel<<<4096, 128, 0, stream>>>(
        tbuf, 4096, 0, 0, DM, ffnout, ln3_g, ln3_b,
        outp, 4096, 0, 0, DM, nullptr, 0, 0, 0, 0);
}

// Round 7
// 738.930 us; speedup vs baseline: 1.1034x; 1.1034x over previous
//
#include <hip/hip_runtime.h>
#include <math.h>

// Problem constants
#define DM    512
#define DI    1024
#define DSN   16
#define DTR   32
#define DFFN  2048
#define BB    8
#define SS    512
#define TTM   1024
#define LCAT  1536
#define NC    32      // scan chunks per sequence

#define ACT_NONE     0
#define ACT_RELU     1
#define ACT_DELTA    3   // split epilogue: n<1024 softplus+bias -> Cb(delta bf16); 1024<=n<1056 -> C2(bc fp32)

typedef __attribute__((ext_vector_type(8))) short short8;
typedef __attribute__((ext_vector_type(4))) float f32x4;

__device__ __forceinline__ unsigned short f2b(float f) {
    unsigned int u = __float_as_uint(f);
    return (unsigned short)((u + 0x7FFFu + ((u >> 16) & 1u)) >> 16);
}
__device__ __forceinline__ float b2f(unsigned short h) {
    return __uint_as_float(((unsigned int)h) << 16);
}
__device__ __forceinline__ float fast_softplus(float v) {
    return (v > 20.f) ? v : __logf(1.f + __expf(v));
}
__device__ __forceinline__ void gld16(const void* g, void* l) {
    __builtin_amdgcn_global_load_lds(
        (const __attribute__((address_space(1))) void*)g,
        (__attribute__((address_space(3))) void*)l, 16, 0, 0);
}

__device__ __forceinline__ int map_row(int m, int mb, int bs, int ro) {
    int q = m / mb;
    return q * bs + ro + (m - q * mb);
}

// ================= bf16 MFMA GEMM: C[m,n] = act(A[row(m),k] * W[n,k] + bias[n])
// A: bf16, row stride K. W: bf16, N x K row-major. Tile 128x128, BK=32.
// LDS layout: XOR-swizzled chunks. Chunk (row r, k-group g) of 16B lives at
// chunk position p = r*4 + (g ^ ((r>>2)&3)).
//  - staging: lane L of a gld16 writes position c = base+L; decode r=c>>2,
//    g=(c&3)^((r>>2)&3). Quad lanes stay within one row's 64B block (XOR only
//    permutes inside the block) -> full 64B-per-quad coalescing.
//  - fragment ds_read_b128: lane(fm=lane&15, g=lane>>4) reads p = R*4+(g^(fm>>2));
//    per 16-lane group p mod 8 hits each value exactly twice -> conflict-free.
__global__ __launch_bounds__(256) void mgemm_kernel(
    const unsigned short* __restrict__ A, int mb, int bs, int ro,
    const unsigned short* __restrict__ W, const float* __restrict__ bias,
    float* __restrict__ Cf, unsigned short* __restrict__ Cb,
    float* __restrict__ C2,
    int N, int K, int act)
{
    __shared__ __align__(16) unsigned short As[128 * 32];
    __shared__ __align__(16) unsigned short Bs[128 * 32];
    int tid = threadIdx.x;
    int lane = tid & 63, wave = tid >> 6;
    int wy = wave >> 1, wx = wave & 1;
    // XCD-band swizzle (gridDim.y assumed divisible by 8)
    int nx = gridDim.x;
    int f = blockIdx.y * nx + blockIdx.x;
    int xcd = f & 7, j2 = f >> 3;
    int bandh = gridDim.y >> 3;
    int m0 = (xcd * bandh + j2 / nx) * 128;
    int n0 = (j2 % nx) * 128;

    // staging: wave stages chunk positions c = wave*128 + j*64 + lane (j=0,1)
    const unsigned short* ga[2];
    const unsigned short* gb[2];
    unsigned short* la[2];
    unsigned short* lb[2];
    #pragma unroll
    for (int j = 0; j < 2; j++) {
        int c  = wave * 128 + j * 64 + lane;
        int r  = c >> 2;                    // tile row 0..127
        int gs = c & 3;
        int g  = gs ^ ((r >> 2) & 3);       // un-swizzled k-chunk
        int arow = map_row(m0 + r, mb, bs, ro);
        ga[j] = A + (size_t)arow * K + g * 8;
        gb[j] = W + (size_t)(n0 + r) * K + g * 8;
        la[j] = As + (size_t)(wave * 128 + j * 64) * 8;   // chunk pos * 8 shorts
        lb[j] = Bs + (size_t)(wave * 128 + j * 64) * 8;
    }
    // fragment read bases (swizzled)
    int fm = lane & 15, fg = lane >> 4;
    int sw = fg ^ (fm >> 2);
    const unsigned short* arp = As + ((size_t)(wy * 64 + fm) * 4 + sw) * 8;
    const unsigned short* brp = Bs + ((size_t)(wx * 64 + fm) * 4 + sw) * 8;

    f32x4 acc[4][4];
    #pragma unroll
    for (int i = 0; i < 4; i++)
        #pragma unroll
        for (int j = 0; j < 4; j++) acc[i][j] = 0.f;

    for (int k0 = 0; k0 < K; k0 += 32) {
        #pragma unroll
        for (int j = 0; j < 2; j++) {
            gld16(ga[j] + k0, la[j]);
            gld16(gb[j] + k0, lb[j]);
        }
        __syncthreads();
        short8 af[4], bfr[4];
        #pragma unroll
        for (int t = 0; t < 4; t++) af[t]  = *(const short8*)(arp + t * 512);
        #pragma unroll
        for (int t = 0; t < 4; t++) bfr[t] = *(const short8*)(brp + t * 512);
        #pragma unroll
        for (int i = 0; i < 4; i++)
            #pragma unroll
            for (int j = 0; j < 4; j++)
                acc[i][j] = __builtin_amdgcn_mfma_f32_16x16x32_bf16(af[i], bfr[j], acc[i][j], 0, 0, 0);
        __syncthreads();
    }

    // epilogue: C/D layout col=lane&15 (n), row=(lane>>4)*4+reg (m)
    int en = lane & 15, em = (lane >> 4) * 4;
    if (act == ACT_DELTA) {
        #pragma unroll
        for (int j = 0; j < 4; j++) {
            int n = n0 + wx * 64 + j * 16 + en;
            bool is_delta = (n < 1024);
            if (!is_delta && n >= 1056) continue;
            float bv = is_delta ? bias[n] : 0.f;
            #pragma unroll
            for (int i = 0; i < 4; i++) {
                int mbase = m0 + wy * 64 + i * 16 + em;
                #pragma unroll
                for (int r = 0; r < 4; r++) {
                    float v = acc[i][j][r] + bv;
                    if (is_delta) {
                        Cb[(size_t)(mbase + r) * 1024 + n] = f2b(fast_softplus(v));
                    } else {
                        C2[(size_t)(mbase + r) * 32 + (n - 1024)] = v;
                    }
                }
            }
        }
        return;
    }
    #pragma unroll
    for (int j = 0; j < 4; j++) {
        int n = n0 + wx * 64 + j * 16 + en;
        float bv = bias ? bias[n] : 0.f;
        #pragma unroll
        for (int i = 0; i < 4; i++) {
            int mbase = m0 + wy * 64 + i * 16 + em;
            #pragma unroll
            for (int r = 0; r < 4; r++) {
                float v = acc[i][j][r] + bv;
                if (act == ACT_RELU) v = v > 0.f ? v : 0.f;
                size_t off = (size_t)(mbase + r) * N + n;
                if (Cb) Cb[off] = f2b(v);
                else    Cf[off] = v;
            }
        }
    }
}

// ================= Wcomb fill: rows 0..1023 = dt_w @ xproj[:32]; 1024..1055 = xproj rows 32..63; rest 0
__global__ void wcomb_kernel(const float* __restrict__ dt_w,
                             const float* __restrict__ xproj,
                             unsigned short* __restrict__ out)
{
    int idx = blockIdx.x * 256 + threadIdx.x;   // n*1024 + k, n < 1152
    int n = idx >> 10, k = idx & 1023;
    float v = 0.f;
    if (n < 1024) {
        #pragma unroll
        for (int r = 0; r < DTR; r++)
            v = fmaf(dt_w[n * DTR + r], xproj[r * 1024 + k], v);
    } else if (n < 1056) {
        v = xproj[(n - 1024 + 32) * 1024 + k];
    }
    out[idx] = f2b(v);
}

// ================= Depthwise causal conv (width 4) + bias + SiLU. bf16 in, bf16 out.
__global__ void conv_silu_kernel(const unsigned short* __restrict__ xz,
                                 const float* __restrict__ cw,
                                 const float* __restrict__ cb,
                                 unsigned short* __restrict__ xc, int L, int total)
{
    int idx = blockIdx.x * blockDim.x + threadIdx.x;
    if (idx >= total) return;
    int d = idx & (DI - 1);
    int r = idx >> 10;     // b*L + l
    int l = r % L;
    float acc = cb[d];
    #pragma unroll
    for (int k = 0; k < 4; k++) {
        int ls = l - 3 + k;
        if (ls >= 0) acc = fmaf(b2f(xz[(size_t)(r - 3 + k) * 2048 + d]), cw[d * 4 + k], acc);
    }
    float s = acc / (1.f + __expf(-acc));
    xc[idx] = f2b(s);
}

// ================= Chunked selective scan (delta bf16)
__global__ __launch_bounds__(256) void scan_part1(
    const unsigned short* __restrict__ delta, const unsigned short* __restrict__ xc,
    const float* __restrict__ bc, const float* __restrict__ A_log,
    float* __restrict__ part_h, float* __restrict__ part_s, int L, int CH)
{
    int tid = threadIdx.x;
    int dblk = blockIdx.x & 3;
    int c    = (blockIdx.x >> 2) & (NC - 1);
    int b    = blockIdx.x >> 7;
    int d    = dblk * 256 + tid;
    float A[DSN];
    #pragma unroll
    for (int s = 0; s < DSN; s++) A[s] = -__expf(A_log[d * DSN + s]);
    float h[DSN];
    #pragma unroll
    for (int s = 0; s < DSN; s++) h[s] = 0.f;
    float ssum = 0.f;
    int l0 = c * CH;
    for (int l = l0; l < l0 + CH; l++) {
        size_t r = (size_t)b * L + l;
        float4 bq[4];
        const float4* bp = (const float4*)(bc + r * 32);
        #pragma unroll
        for (int q = 0; q < 4; q++) bq[q] = bp[q];
        const float* Bm = (const float*)&bq[0];
        float dl = b2f(delta[r * DI + d]);
        float u  = b2f(xc[r * DI + d]);
        float du = dl * u;
        ssum += dl;
        #pragma unroll
        for (int s = 0; s < DSN; s++)
            h[s] = fmaf(__expf(dl * A[s]), h[s], du * Bm[s]);
    }
    size_t base = ((size_t)(b * NC + c) * DI + d) * DSN;
    #pragma unroll
    for (int q = 0; q < 4; q++)
        ((float4*)(part_h + base))[q] = make_float4(h[q*4], h[q*4+1], h[q*4+2], h[q*4+3]);
    part_s[(size_t)(b * NC + c) * DI + d] = ssum;
}

__global__ __launch_bounds__(256) void scan_combine(
    const float* __restrict__ A_log,
    float* __restrict__ part_h, const float* __restrict__ part_s)
{
    int idx = blockIdx.x * 256 + threadIdx.x;
    int b = idx >> 10, d = idx & (DI - 1);
    float A[DSN];
    #pragma unroll
    for (int s = 0; s < DSN; s++) A[s] = -__expf(A_log[d * DSN + s]);
    float h[DSN];
    #pragma unroll
    for (int s = 0; s < DSN; s++) h[s] = 0.f;
    for (int c = 0; c < NC; c++) {
        size_t base = ((size_t)(b * NC + c) * DI + d) * DSN;
        float4 ph4[4];
        #pragma unroll
        for (int q = 0; q < 4; q++) ph4[q] = ((const float4*)(part_h + base))[q];
        const float* ph = (const float*)&ph4[0];
        float S = part_s[(size_t)(b * NC + c) * DI + d];
        #pragma unroll
        for (int q = 0; q < 4; q++)
            ((float4*)(part_h + base))[q] = make_float4(h[q*4], h[q*4+1], h[q*4+2], h[q*4+3]);
        #pragma unroll
        for (int s = 0; s < DSN; s++)
            h[s] = fmaf(__expf(A[s] * S), h[s], ph[s]);
    }
}

// pass 3: rescan chunk from h_in, emit gated output to bf16 buffer.
__global__ __launch_bounds__(256) void scan_part2(
    const unsigned short* __restrict__ delta, const unsigned short* __restrict__ xc,
    const float* __restrict__ bc, const unsigned short* __restrict__ xz,
    const float* __restrict__ A_log, const float* __restrict__ Dv,
    const float* __restrict__ part_h,
    unsigned short* __restrict__ out, int L, int CH)
{
    int tid = threadIdx.x;
    int dblk = blockIdx.x & 3;
    int c    = (blockIdx.x >> 2) & (NC - 1);
    int b    = blockIdx.x >> 7;
    int d    = dblk * 256 + tid;
    float A[DSN];
    #pragma unroll
    for (int s = 0; s < DSN; s++) A[s] = -__expf(A_log[d * DSN + s]);
    float Dvd = Dv[d];
    size_t base = ((size_t)(b * NC + c) * DI + d) * DSN;
    float h4[4][4];
    #pragma unroll
    for (int q = 0; q < 4; q++) *((float4*)h4[q]) = ((const float4*)(part_h + base))[q];
    float h[DSN];
    #pragma unroll
    for (int s = 0; s < DSN; s++) h[s] = h4[s >> 2][s & 3];
    int l0 = c * CH;
    for (int l = l0; l < l0 + CH; l++) {
        size_t r = (size_t)b * L + l;
        float4 bq[8];
        const float4* bp = (const float4*)(bc + r * 32);
        #pragma unroll
        for (int q = 0; q < 8; q++) bq[q] = bp[q];
        const float* Bm = (const float*)&bq[0];
        const float* Cm = Bm + DSN;
        float dl = b2f(delta[r * DI + d]);
        float u  = b2f(xc[r * DI + d]);
        float du = dl * u;
        float y = 0.f;
        #pragma unroll
        for (int s = 0; s < DSN; s++) {
            h[s] = fmaf(__expf(dl * A[s]), h[s], du * Bm[s]);
            y = fmaf(h[s], Cm[s], y);
        }
        float z = b2f(xz[r * 2048 + DI + d]);
        float sil = z / (1.f + __expf(-z));
        out[r * DI + d] = f2b((y + u * Dvd) * sil);
    }
}

// ================= residual add + LayerNorm; optional fp32 and bf16 outputs
__global__ __launch_bounds__(128) void addln_kernel(
    const float* __restrict__ a, int amb, int absd, int aro, int lda,
    const float* __restrict__ bsrc,
    const float* __restrict__ g, const float* __restrict__ be,
    float* __restrict__ outf, int omb, int obsd, int oro, int ldo,
    unsigned short* __restrict__ outb, int bmb, int bbsd, int bro, int ldb)
{
    int m = blockIdx.x, t = threadIdx.x;
    int ar = map_row(m, amb, absd, aro);
    float4 x4 = ((const float4*)(a + (size_t)ar * lda))[t];
    float4 y4 = ((const float4*)(bsrc + (size_t)m * DM))[t];
    float v[4] = {x4.x + y4.x, x4.y + y4.y, x4.z + y4.z, x4.w + y4.w};
    float sum = v[0] + v[1] + v[2] + v[3];
    float sq  = v[0]*v[0] + v[1]*v[1] + v[2]*v[2] + v[3]*v[3];
    #pragma unroll
    for (int o = 32; o > 0; o >>= 1) {
        sum += __shfl_down(sum, o);
        sq  += __shfl_down(sq, o);
    }
    __shared__ float s0[2], s1[2];
    if ((t & 63) == 0) { s0[t >> 6] = sum; s1[t >> 6] = sq; }
    __syncthreads();
    float tot = s0[0] + s0[1];
    float tsq = s1[0] + s1[1];
    float mu = tot * (1.f / DM);
    float var = tsq * (1.f / DM) - mu * mu;
    float rs = rsqrtf(var + 1e-6f);
    float4 g4 = ((const float4*)g)[t];
    float4 b4 = ((const float4*)be)[t];
    float o0 = (v[0] - mu) * rs * g4.x + b4.x;
    float o1 = (v[1] - mu) * rs * g4.y + b4.y;
    float o2 = (v[2] - mu) * rs * g4.z + b4.z;
    float o3 = (v[3] - mu) * rs * g4.w + b4.w;
    if (outf) {
        int orow = map_row(m, omb, obsd, oro);
        ((float4*)(outf + (size_t)orow * ldo))[t] = make_float4(o0, o1, o2, o3);
    }
    if (outb) {
        int brow = map_row(m, bmb, bbsd, bro);
        ((ushort4*)(outb + (size_t)brow * ldb))[t] =
            make_ushort4(f2b(o0), f2b(o1), f2b(o2), f2b(o3));
    }
}

// ================= fp32 -> bf16 convert (n4 float4 groups)
__global__ void f2b_kernel(const float* __restrict__ in, unsigned short* __restrict__ out, int n4)
{
    int i = blockIdx.x * 256 + threadIdx.x;
    if (i >= n4) return;
    float4 v = ((const float4*)in)[i];
    ((ushort4*)out)[i] = make_ushort4(f2b(v.x), f2b(v.y), f2b(v.z), f2b(v.w));
}

// ================= merged 6-weight fp32 -> bf16 convert (contiguous bf16 output region)
struct W6 { const float* p[6]; };
__global__ void wconv_kernel(W6 w, unsigned short* __restrict__ out)
{
    const int cum[7] = {0, 262144, 524288, 655360, 786432, 1048576, 1310720};
    int i = blockIdx.x * 256 + threadIdx.x;
    if (i >= 1310720) return;
    int seg = 0;
    #pragma unroll
    for (int s = 1; s < 6; s++) seg += (i >= cum[s]);
    float4 v = ((const float4*)w.p[seg])[i - cum[seg]];
    ((ushort4*)out)[i] = make_ushort4(f2b(v.x), f2b(v.y), f2b(v.z), f2b(v.w));
}

// ================= memory(fp32) -> catb(bf16) rows [b*1536 + 0..1023]
__global__ void mem2catb_kernel(const float* __restrict__ mem, unsigned short* __restrict__ catb)
{
    int f = blockIdx.x * blockDim.x + threadIdx.x;
    const int total = BB * TTM * DM / 4;
    if (f >= total) return;
    const int per_b = TTM * DM / 4;
    int b = f / per_b, rem = f - b * per_b;
    float4 v = ((const float4*)mem)[f];
    ((ushort4*)catb)[(size_t)b * (LCAT * DM / 4) + rem] =
        make_ushort4(f2b(v.x), f2b(v.y), f2b(v.z), f2b(v.w));
}

static void run_scan(const unsigned short* dltb, const unsigned short* xcb, const float* bc,
                     const unsigned short* xzb, const float* A_log, const float* Dv,
                     float* part_h, float* part_s, unsigned short* out, int L,
                     hipStream_t stream)
{
    int CH = L / NC;
    int blocks = BB * NC * (DI / 256);
    scan_part1<<<blocks, 256, 0, stream>>>(dltb, xcb, bc, A_log, part_h, part_s, L, CH);
    scan_combine<<<BB * DI / 256, 256, 0, stream>>>(A_log, part_h, part_s);
    scan_part2<<<blocks, 256, 0, stream>>>(dltb, xcb, bc, xzb, A_log, Dv, part_h, out, L, CH);
}

extern "C" void kernel_launch(void* const* d_in, const int* in_sizes, int n_in,
                              void* d_out, int out_size, void* d_ws, size_t ws_size,
                              hipStream_t stream)
{
    const float* tgt       = (const float*)d_in[0];
    const float* memory    = (const float*)d_in[1];
    const float* s_in_w    = (const float*)d_in[2];
    const float* s_conv_w  = (const float*)d_in[3];
    const float* s_conv_b  = (const float*)d_in[4];
    const float* s_xproj_w = (const float*)d_in[5];
    const float* s_dt_w    = (const float*)d_in[6];
    const float* s_dt_b    = (const float*)d_in[7];
    const float* s_A_log   = (const float*)d_in[8];
    const float* s_D_vec   = (const float*)d_in[9];
    const float* s_out_w   = (const float*)d_in[10];
    const float* c_in_w    = (const float*)d_in[11];
    const float* c_conv_w  = (const float*)d_in[12];
    const float* c_conv_b  = (const float*)d_in[13];
    const float* c_xproj_w = (const float*)d_in[14];
    const float* c_dt_w    = (const float*)d_in[15];
    const float* c_dt_b    = (const float*)d_in[16];
    const float* c_A_log   = (const float*)d_in[17];
    const float* c_D_vec   = (const float*)d_in[18];
    const float* c_out_w   = (const float*)d_in[19];
    const float* ln1_g     = (const float*)d_in[20];
    const float* ln1_b     = (const float*)d_in[21];
    const float* ln2_g     = (const float*)d_in[22];
    const float* ln2_b     = (const float*)d_in[23];
    const float* ln3_g     = (const float*)d_in[24];
    const float* ln3_b     = (const float*)d_in[25];
    const float* ffn_w1    = (const float*)d_in[26];
    const float* ffn_b1    = (const float*)d_in[27];
    const float* ffn_w2    = (const float*)d_in[28];
    const float* ffn_b2    = (const float*)d_in[29];
    float* outp = (float*)d_out;

    // ---- workspace layout ----
    // fp32 region (floats): 11,141,120 floats = 44.6 MB
    float* ws     = (float*)d_ws;
    float* bc     = ws;                     // 393216  (12288 x 32: B|C)
    float* proj   = bc     + 393216;        // 2097152
    float* t1     = proj   + 2097152;       // 2097152
    float* tbuf   = t1     + 2097152;       // 2097152
    float* part_h = tbuf   + 2097152;       // 4194304
    float* part_s = part_h + 4194304;       // 262144
    // bf16 region (ushorts): 81,002,496 elems = 162 MB ; total ~207 MB
    unsigned short* ub      = (unsigned short*)(part_s + 262144);
    unsigned short* dltb    = ub;                   // 12582912 (bf16 delta; ffnout aliases)
    unsigned short* catb    = dltb    + 12582912;   // 6291456
    unsigned short* tgtb    = catb    + 6291456;    // 2097152
    unsigned short* xzb     = tgtb    + 2097152;    // 25165824 (also fbuf alias)
    unsigned short* xcb     = xzb     + 25165824;   // 12582912
    unsigned short* ygb     = xcb     + 12582912;   // 12582912
    unsigned short* tbbf    = ygb     + 12582912;   // 2097152
    unsigned short* s_in_wb = tbbf    + 2097152;    // 1048576  (6-weight block, contiguous)
    unsigned short* c_in_wb = s_in_wb + 1048576;    // 1048576
    unsigned short* s_out_wb= c_in_wb + 1048576;    // 524288
    unsigned short* c_out_wb= s_out_wb+ 524288;     // 524288
    unsigned short* w1b     = c_out_wb+ 524288;     // 1048576
    unsigned short* w2b     = w1b     + 1048576;    // 1048576
    unsigned short* wcomb_s = w2b     + 1048576;    // 1179648 (1152 x 1024)
    unsigned short* wcomb_c = wcomb_s + 1179648;    // 1179648
    unsigned short* fbuf    = xzb;                  // FFN hidden alias
    float* ffnout = (float*)dltb;                   // alias (dltb dead after cross scan)

    // ---- converts & combined-weight fills ----
    f2b_kernel<<<(2097152/4 + 255)/256, 256, 0, stream>>>(tgt, tgtb, 2097152/4);
    mem2catb_kernel<<<(BB*TTM*DM/4 + 255)/256, 256, 0, stream>>>(memory, catb);
    {
        W6 w; w.p[0]=s_in_w; w.p[1]=c_in_w; w.p[2]=s_out_w; w.p[3]=c_out_w; w.p[4]=ffn_w1; w.p[5]=ffn_w2;
        wconv_kernel<<<(1310720 + 255)/256, 256, 0, stream>>>(w, s_in_wb);
    }
    wcomb_kernel<<<(1152*1024)/256, 256, 0, stream>>>(s_dt_w, s_xproj_w, wcomb_s);
    wcomb_kernel<<<(1152*1024)/256, 256, 0, stream>>>(c_dt_w, c_xproj_w, wcomb_c);

    // ---- self mamba (L=512, M=4096) ----
    mgemm_kernel<<<dim3(2048/128, 4096/128), 256, 0, stream>>>(
        tgtb, 4096, 0, 0, s_in_wb, nullptr, nullptr, xzb, nullptr, 2048, 512, ACT_NONE);
    conv_silu_kernel<<<(BB*SS*DI + 255)/256, 256, 0, stream>>>(xzb, s_conv_w, s_conv_b, xcb, SS, BB*SS*DI);
    // combined delta + BC GEMM: M=4096, Ncomb=1152, K=1024
    mgemm_kernel<<<dim3(1152/128, 4096/128), 256, 0, stream>>>(
        xcb, 4096, 0, 0, wcomb_s, s_dt_b, nullptr, dltb, bc, 1152, 1024, ACT_DELTA);
    run_scan(dltb, xcb, bc, xzb, s_A_log, s_D_vec, part_h, part_s, ygb, SS, stream);
    mgemm_kernel<<<dim3(512/128, 4096/128), 256, 0, stream>>>(
        ygb, 4096, 0, 0, s_out_wb, nullptr, proj, nullptr, nullptr, 512, 1024, ACT_NONE);
    // t = LN(tgt + proj): fp32 -> t1, bf16 -> catb rows [b*1536+1024+l]
    addln_kernel<<<4096, 128, 0, stream>>>(
        tgt, 4096, 0, 0, DM, proj, ln1_g, ln1_b,
        t1, 4096, 0, 0, DM, catb, 512, 1536, 1024, DM);

    // ---- cross mamba (L=1536, M=12288) ----
    mgemm_kernel<<<dim3(2048/128, 12288/128), 256, 0, stream>>>(
        catb, 12288, 0, 0, c_in_wb, nullptr, nullptr, xzb, nullptr, 2048, 512, ACT_NONE);
    conv_silu_kernel<<<(BB*LCAT*DI + 255)/256, 256, 0, stream>>>(xzb, c_conv_w, c_conv_b, xcb, LCAT, BB*LCAT*DI);
    mgemm_kernel<<<dim3(1152/128, 12288/128), 256, 0, stream>>>(
        xcb, 12288, 0, 0, wcomb_c, c_dt_b, nullptr, dltb, bc, 1152, 1024, ACT_DELTA);
    run_scan(dltb, xcb, bc, xzb, c_A_log, c_D_vec, part_h, part_s, ygb, LCAT, stream);
    // out proj over last S rows per batch: row(m) = (m/512)*1536 + 1024 + m%512
    mgemm_kernel<<<dim3(512/128, 4096/128), 256, 0, stream>>>(
        ygb, 512, 1536, 1024, c_out_wb, nullptr, proj, nullptr, nullptr, 512, 1024, ACT_NONE);
    addln_kernel<<<4096, 128, 0, stream>>>(
        t1, 4096, 0, 0, DM, proj, ln2_g, ln2_b,
        tbuf, 4096, 0, 0, DM, tbbf, 4096, 0, 0, DM);

    // ---- FFN ----
    mgemm_kernel<<<dim3(2048/128, 4096/128), 256, 0, stream>>>(
        tbbf, 4096, 0, 0, w1b, ffn_b1, nullptr, fbuf, nullptr, 2048, 512, ACT_RELU);
    mgemm_kernel<<<dim3(512/128, 4096/128), 256, 0, stream>>>(
        fbuf, 4096, 0, 0, w2b, ffn_b2, ffnout, nullptr, nullptr, 512, 2048, ACT_NONE);
    addln_kernel<<<4096, 128, 0, stream>>>(
        tbuf, 4096, 0, 0, DM, ffnout, ln3_g, ln3_b,
        outp, 4096, 0, 0, DM, nullptr, 0, 0, 0, 0);
}

// Round 8
// 731.667 us; speedup vs baseline: 1.1143x; 1.0099x over previous
//
#include <hip/hip_runtime.h>
#include <math.h>

// Problem constants
#define DM    512
#define DI    1024
#define DSN   16
#define DTR   32
#define DFFN  2048
#define BB    8
#define SS    512
#define TTM   1024
#define LCAT  1536
#define NC    32      // scan chunks per sequence

#define ACT_NONE     0
#define ACT_RELU     1
#define ACT_DELTA    3   // split epilogue: n<1024 softplus+bias -> Cb(delta bf16); 1024<=n<1056 -> C2(bc fp32)

typedef __attribute__((ext_vector_type(8))) short short8;
typedef __attribute__((ext_vector_type(4))) float f32x4;

__device__ __forceinline__ unsigned short f2b(float f) {
    unsigned int u = __float_as_uint(f);
    return (unsigned short)((u + 0x7FFFu + ((u >> 16) & 1u)) >> 16);
}
__device__ __forceinline__ float b2f(unsigned short h) {
    return __uint_as_float(((unsigned int)h) << 16);
}
__device__ __forceinline__ float fast_softplus(float v) {
    return (v > 20.f) ? v : __logf(1.f + __expf(v));
}
__device__ __forceinline__ void gld16(const void* g, void* l) {
    __builtin_amdgcn_global_load_lds(
        (const __attribute__((address_space(1))) void*)g,
        (__attribute__((address_space(3))) void*)l, 16, 0, 0);
}

__device__ __forceinline__ int map_row(int m, int mb, int bs, int ro) {
    int q = m / mb;
    return q * bs + ro + (m - q * mb);
}

// ================= bf16 MFMA GEMM: C[m,n] = act(A[row(m),k] * W[n,k] + bias[n])
// A: bf16, row stride K. W: bf16, N x K row-major. Tile 128x128, BK=32.
// LDS layout: QUAD-level XOR swizzle. Chunk (row r, k-group g) of 16B lives at
// chunk position p = r*4 + (g ^ ((r>>1)&3)).
//  - staging: lane L writes position c = base+L; decode r=c>>2, g=(c&3)^((r>>1)&3).
//    A staging quad shares one row, g covers {0..3} -> 64B contiguous -> coalesced.
//  - fragment ds_read_b128: lane(fm,fg) reads p=(base+fm)*4 + (fg^((fm>>1)&3));
//    a read quad (4 consecutive fm, fixed fg) hits 4 DISTINCT bank-quads
//    {fg^a, 4+fg^a, fg^(a^1), 4+fg^(a^1)} -> conflict-free at quad granularity
//    (R4/R5/R7 all showed exactly 4.0 conflict-cycles per b128 when quads
//    degenerated to 2 bank-quads; R6 showed 0 with 4 distinct).
__global__ __launch_bounds__(256) void mgemm_kernel(
    const unsigned short* __restrict__ A, int mb, int bs, int ro,
    const unsigned short* __restrict__ W, const float* __restrict__ bias,
    float* __restrict__ Cf, unsigned short* __restrict__ Cb,
    float* __restrict__ C2,
    int N, int K, int act)
{
    __shared__ __align__(16) unsigned short As[128 * 32];
    __shared__ __align__(16) unsigned short Bs[128 * 32];
    int tid = threadIdx.x;
    int lane = tid & 63, wave = tid >> 6;
    int wy = wave >> 1, wx = wave & 1;
    // XCD-band swizzle (gridDim.y assumed divisible by 8)
    int nx = gridDim.x;
    int f = blockIdx.y * nx + blockIdx.x;
    int xcd = f & 7, j2 = f >> 3;
    int bandh = gridDim.y >> 3;
    int m0 = (xcd * bandh + j2 / nx) * 128;
    int n0 = (j2 % nx) * 128;

    // staging: wave stages chunk positions c = wave*128 + j*64 + lane (j=0,1)
    const unsigned short* ga[2];
    const unsigned short* gb[2];
    unsigned short* la[2];
    unsigned short* lb[2];
    #pragma unroll
    for (int j = 0; j < 2; j++) {
        int c  = wave * 128 + j * 64 + lane;
        int r  = c >> 2;                    // tile row 0..127
        int gs = c & 3;
        int g  = gs ^ ((r >> 1) & 3);       // un-swizzled k-chunk (quad-level XOR)
        int arow = map_row(m0 + r, mb, bs, ro);
        ga[j] = A + (size_t)arow * K + g * 8;
        gb[j] = W + (size_t)(n0 + r) * K + g * 8;
        la[j] = As + (size_t)(wave * 128 + j * 64) * 8;   // chunk pos * 8 shorts
        lb[j] = Bs + (size_t)(wave * 128 + j * 64) * 8;
    }
    // fragment read bases (swizzled)
    int fm = lane & 15, fg = lane >> 4;
    int sw = fg ^ ((fm >> 1) & 3);
    const unsigned short* arp = As + ((size_t)(wy * 64 + fm) * 4 + sw) * 8;
    const unsigned short* brp = Bs + ((size_t)(wx * 64 + fm) * 4 + sw) * 8;

    f32x4 acc[4][4];
    #pragma unroll
    for (int i = 0; i < 4; i++)
        #pragma unroll
        for (int j = 0; j < 4; j++) acc[i][j] = 0.f;

    for (int k0 = 0; k0 < K; k0 += 32) {
        #pragma unroll
        for (int j = 0; j < 2; j++) {
            gld16(ga[j] + k0, la[j]);
            gld16(gb[j] + k0, lb[j]);
        }
        __syncthreads();
        short8 af[4], bfr[4];
        #pragma unroll
        for (int t = 0; t < 4; t++) af[t]  = *(const short8*)(arp + t * 512);
        #pragma unroll
        for (int t = 0; t < 4; t++) bfr[t] = *(const short8*)(brp + t * 512);
        #pragma unroll
        for (int i = 0; i < 4; i++)
            #pragma unroll
            for (int j = 0; j < 4; j++)
                acc[i][j] = __builtin_amdgcn_mfma_f32_16x16x32_bf16(af[i], bfr[j], acc[i][j], 0, 0, 0);
        __syncthreads();
    }

    // epilogue: C/D layout col=lane&15 (n), row=(lane>>4)*4+reg (m)
    int en = lane & 15, em = (lane >> 4) * 4;
    if (act == ACT_DELTA) {
        #pragma unroll
        for (int j = 0; j < 4; j++) {
            int n = n0 + wx * 64 + j * 16 + en;
            bool is_delta = (n < 1024);
            if (!is_delta && n >= 1056) continue;
            float bv = is_delta ? bias[n] : 0.f;
            #pragma unroll
            for (int i = 0; i < 4; i++) {
                int mbase = m0 + wy * 64 + i * 16 + em;
                #pragma unroll
                for (int r = 0; r < 4; r++) {
                    float v = acc[i][j][r] + bv;
                    if (is_delta) {
                        Cb[(size_t)(mbase + r) * 1024 + n] = f2b(fast_softplus(v));
                    } else {
                        C2[(size_t)(mbase + r) * 32 + (n - 1024)] = v;
                    }
                }
            }
        }
        return;
    }
    #pragma unroll
    for (int j = 0; j < 4; j++) {
        int n = n0 + wx * 64 + j * 16 + en;
        float bv = bias ? bias[n] : 0.f;
        #pragma unroll
        for (int i = 0; i < 4; i++) {
            int mbase = m0 + wy * 64 + i * 16 + em;
            #pragma unroll
            for (int r = 0; r < 4; r++) {
                float v = acc[i][j][r] + bv;
                if (act == ACT_RELU) v = v > 0.f ? v : 0.f;
                size_t off = (size_t)(mbase + r) * N + n;
                if (Cb) Cb[off] = f2b(v);
                else    Cf[off] = v;
            }
        }
    }
}

// ================= Wcomb fill: rows 0..1023 = dt_w @ xproj[:32]; 1024..1055 = xproj rows 32..63; rest 0
__global__ void wcomb_kernel(const float* __restrict__ dt_w,
                             const float* __restrict__ xproj,
                             unsigned short* __restrict__ out)
{
    int idx = blockIdx.x * 256 + threadIdx.x;   // n*1024 + k, n < 1152
    int n = idx >> 10, k = idx & 1023;
    float v = 0.f;
    if (n < 1024) {
        #pragma unroll
        for (int r = 0; r < DTR; r++)
            v = fmaf(dt_w[n * DTR + r], xproj[r * 1024 + k], v);
    } else if (n < 1056) {
        v = xproj[(n - 1024 + 32) * 1024 + k];
    }
    out[idx] = f2b(v);
}

// ================= Depthwise causal conv (width 4) + bias + SiLU. bf16 in, bf16 out.
__global__ void conv_silu_kernel(const unsigned short* __restrict__ xz,
                                 const float* __restrict__ cw,
                                 const float* __restrict__ cb,
                                 unsigned short* __restrict__ xc, int L, int total)
{
    int idx = blockIdx.x * blockDim.x + threadIdx.x;
    if (idx >= total) return;
    int d = idx & (DI - 1);
    int r = idx >> 10;     // b*L + l
    int l = r % L;
    float acc = cb[d];
    #pragma unroll
    for (int k = 0; k < 4; k++) {
        int ls = l - 3 + k;
        if (ls >= 0) acc = fmaf(b2f(xz[(size_t)(r - 3 + k) * 2048 + d]), cw[d * 4 + k], acc);
    }
    float s = acc / (1.f + __expf(-acc));
    xc[idx] = f2b(s);
}

// ================= Chunked selective scan (delta bf16)
__global__ __launch_bounds__(256) void scan_part1(
    const unsigned short* __restrict__ delta, const unsigned short* __restrict__ xc,
    const float* __restrict__ bc, const float* __restrict__ A_log,
    float* __restrict__ part_h, float* __restrict__ part_s, int L, int CH)
{
    int tid = threadIdx.x;
    int dblk = blockIdx.x & 3;
    int c    = (blockIdx.x >> 2) & (NC - 1);
    int b    = blockIdx.x >> 7;
    int d    = dblk * 256 + tid;
    float A[DSN];
    #pragma unroll
    for (int s = 0; s < DSN; s++) A[s] = -__expf(A_log[d * DSN + s]);
    float h[DSN];
    #pragma unroll
    for (int s = 0; s < DSN; s++) h[s] = 0.f;
    float ssum = 0.f;
    int l0 = c * CH;
    for (int l = l0; l < l0 + CH; l++) {
        size_t r = (size_t)b * L + l;
        float4 bq[4];
        const float4* bp = (const float4*)(bc + r * 32);
        #pragma unroll
        for (int q = 0; q < 4; q++) bq[q] = bp[q];
        const float* Bm = (const float*)&bq[0];
        float dl = b2f(delta[r * DI + d]);
        float u  = b2f(xc[r * DI + d]);
        float du = dl * u;
        ssum += dl;
        #pragma unroll
        for (int s = 0; s < DSN; s++)
            h[s] = fmaf(__expf(dl * A[s]), h[s], du * Bm[s]);
    }
    size_t base = ((size_t)(b * NC + c) * DI + d) * DSN;
    #pragma unroll
    for (int q = 0; q < 4; q++)
        ((float4*)(part_h + base))[q] = make_float4(h[q*4], h[q*4+1], h[q*4+2], h[q*4+3]);
    part_s[(size_t)(b * NC + c) * DI + d] = ssum;
}

__global__ __launch_bounds__(256) void scan_combine(
    const float* __restrict__ A_log,
    float* __restrict__ part_h, const float* __restrict__ part_s)
{
    int idx = blockIdx.x * 256 + threadIdx.x;
    int b = idx >> 10, d = idx & (DI - 1);
    float A[DSN];
    #pragma unroll
    for (int s = 0; s < DSN; s++) A[s] = -__expf(A_log[d * DSN + s]);
    float h[DSN];
    #pragma unroll
    for (int s = 0; s < DSN; s++) h[s] = 0.f;
    for (int c = 0; c < NC; c++) {
        size_t base = ((size_t)(b * NC + c) * DI + d) * DSN;
        float4 ph4[4];
        #pragma unroll
        for (int q = 0; q < 4; q++) ph4[q] = ((const float4*)(part_h + base))[q];
        const float* ph = (const float*)&ph4[0];
        float S = part_s[(size_t)(b * NC + c) * DI + d];
        #pragma unroll
        for (int q = 0; q < 4; q++)
            ((float4*)(part_h + base))[q] = make_float4(h[q*4], h[q*4+1], h[q*4+2], h[q*4+3]);
        #pragma unroll
        for (int s = 0; s < DSN; s++)
            h[s] = fmaf(__expf(A[s] * S), h[s], ph[s]);
    }
}

// pass 3: rescan chunk from h_in, emit gated output to bf16 buffer.
__global__ __launch_bounds__(256) void scan_part2(
    const unsigned short* __restrict__ delta, const unsigned short* __restrict__ xc,
    const float* __restrict__ bc, const unsigned short* __restrict__ xz,
    const float* __restrict__ A_log, const float* __restrict__ Dv,
    const float* __restrict__ part_h,
    unsigned short* __restrict__ out, int L, int CH)
{
    int tid = threadIdx.x;
    int dblk = blockIdx.x & 3;
    int c    = (blockIdx.x >> 2) & (NC - 1);
    int b    = blockIdx.x >> 7;
    int d    = dblk * 256 + tid;
    float A[DSN];
    #pragma unroll
    for (int s = 0; s < DSN; s++) A[s] = -__expf(A_log[d * DSN + s]);
    float Dvd = Dv[d];
    size_t base = ((size_t)(b * NC + c) * DI + d) * DSN;
    float h4[4][4];
    #pragma unroll
    for (int q = 0; q < 4; q++) *((float4*)h4[q]) = ((const float4*)(part_h + base))[q];
    float h[DSN];
    #pragma unroll
    for (int s = 0; s < DSN; s++) h[s] = h4[s >> 2][s & 3];
    int l0 = c * CH;
    for (int l = l0; l < l0 + CH; l++) {
        size_t r = (size_t)b * L + l;
        float4 bq[8];
        const float4* bp = (const float4*)(bc + r * 32);
        #pragma unroll
        for (int q = 0; q < 8; q++) bq[q] = bp[q];
        const float* Bm = (const float*)&bq[0];
        const float* Cm = Bm + DSN;
        float dl = b2f(delta[r * DI + d]);
        float u  = b2f(xc[r * DI + d]);
        float du = dl * u;
        float y = 0.f;
        #pragma unroll
        for (int s = 0; s < DSN; s++) {
            h[s] = fmaf(__expf(dl * A[s]), h[s], du * Bm[s]);
            y = fmaf(h[s], Cm[s], y);
        }
        float z = b2f(xz[r * 2048 + DI + d]);
        float sil = z / (1.f + __expf(-z));
        out[r * DI + d] = f2b((y + u * Dvd) * sil);
    }
}

// ================= residual add + LayerNorm; optional fp32 and bf16 outputs
__global__ __launch_bounds__(128) void addln_kernel(
    const float* __restrict__ a, int amb, int absd, int aro, int lda,
    const float* __restrict__ bsrc,
    const float* __restrict__ g, const float* __restrict__ be,
    float* __restrict__ outf, int omb, int obsd, int oro, int ldo,
    unsigned short* __restrict__ outb, int bmb, int bbsd, int bro, int ldb)
{
    int m = blockIdx.x, t = threadIdx.x;
    int ar = map_row(m, amb, absd, aro);
    float4 x4 = ((const float4*)(a + (size_t)ar * lda))[t];
    float4 y4 = ((const float4*)(bsrc + (size_t)m * DM))[t];
    float v[4] = {x4.x + y4.x, x4.y + y4.y, x4.z + y4.z, x4.w + y4.w};
    float sum = v[0] + v[1] + v[2] + v[3];
    float sq  = v[0]*v[0] + v[1]*v[1] + v[2]*v[2] + v[3]*v[3];
    #pragma unroll
    for (int o = 32; o > 0; o >>= 1) {
        sum += __shfl_down(sum, o);
        sq  += __shfl_down(sq, o);
    }
    __shared__ float s0[2], s1[2];
    if ((t & 63) == 0) { s0[t >> 6] = sum; s1[t >> 6] = sq; }
    __syncthreads();
    float tot = s0[0] + s0[1];
    float tsq = s1[0] + s1[1];
    float mu = tot * (1.f / DM);
    float var = tsq * (1.f / DM) - mu * mu;
    float rs = rsqrtf(var + 1e-6f);
    float4 g4 = ((const float4*)g)[t];
    float4 b4 = ((const float4*)be)[t];
    float o0 = (v[0] - mu) * rs * g4.x + b4.x;
    float o1 = (v[1] - mu) * rs * g4.y + b4.y;
    float o2 = (v[2] - mu) * rs * g4.z + b4.z;
    float o3 = (v[3] - mu) * rs * g4.w + b4.w;
    if (outf) {
        int orow = map_row(m, omb, obsd, oro);
        ((float4*)(outf + (size_t)orow * ldo))[t] = make_float4(o0, o1, o2, o3);
    }
    if (outb) {
        int brow = map_row(m, bmb, bbsd, bro);
        ((ushort4*)(outb + (size_t)brow * ldb))[t] =
            make_ushort4(f2b(o0), f2b(o1), f2b(o2), f2b(o3));
    }
}

// ================= fp32 -> bf16 convert (n4 float4 groups)
__global__ void f2b_kernel(const float* __restrict__ in, unsigned short* __restrict__ out, int n4)
{
    int i = blockIdx.x * 256 + threadIdx.x;
    if (i >= n4) return;
    float4 v = ((const float4*)in)[i];
    ((ushort4*)out)[i] = make_ushort4(f2b(v.x), f2b(v.y), f2b(v.z), f2b(v.w));
}

// ================= merged 6-weight fp32 -> bf16 convert (contiguous bf16 output region)
struct W6 { const float* p[6]; };
__global__ void wconv_kernel(W6 w, unsigned short* __restrict__ out)
{
    const int cum[7] = {0, 262144, 524288, 655360, 786432, 1048576, 1310720};
    int i = blockIdx.x * 256 + threadIdx.x;
    if (i >= 1310720) return;
    int seg = 0;
    #pragma unroll
    for (int s = 1; s < 6; s++) seg += (i >= cum[s]);
    float4 v = ((const float4*)w.p[seg])[i - cum[seg]];
    ((ushort4*)out)[i] = make_ushort4(f2b(v.x), f2b(v.y), f2b(v.z), f2b(v.w));
}

// ================= memory(fp32) -> catb(bf16) rows [b*1536 + 0..1023]
__global__ void mem2catb_kernel(const float* __restrict__ mem, unsigned short* __restrict__ catb)
{
    int f = blockIdx.x * blockDim.x + threadIdx.x;
    const int total = BB * TTM * DM / 4;
    if (f >= total) return;
    const int per_b = TTM * DM / 4;
    int b = f / per_b, rem = f - b * per_b;
    float4 v = ((const float4*)mem)[f];
    ((ushort4*)catb)[(size_t)b * (LCAT * DM / 4) + rem] =
        make_ushort4(f2b(v.x), f2b(v.y), f2b(v.z), f2b(v.w));
}

static void run_scan(const unsigned short* dltb, const unsigned short* xcb, const float* bc,
                     const unsigned short* xzb, const float* A_log, const float* Dv,
                     float* part_h, float* part_s, unsigned short* out, int L,
                     hipStream_t stream)
{
    int CH = L / NC;
    int blocks = BB * NC * (DI / 256);
    scan_part1<<<blocks, 256, 0, stream>>>(dltb, xcb, bc, A_log, part_h, part_s, L, CH);
    scan_combine<<<BB * DI / 256, 256, 0, stream>>>(A_log, part_h, part_s);
    scan_part2<<<blocks, 256, 0, stream>>>(dltb, xcb, bc, xzb, A_log, Dv, part_h, out, L, CH);
}

extern "C" void kernel_launch(void* const* d_in, const int* in_sizes, int n_in,
                              void* d_out, int out_size, void* d_ws, size_t ws_size,
                              hipStream_t stream)
{
    const float* tgt       = (const float*)d_in[0];
    const float* memory    = (const float*)d_in[1];
    const float* s_in_w    = (const float*)d_in[2];
    const float* s_conv_w  = (const float*)d_in[3];
    const float* s_conv_b  = (const float*)d_in[4];
    const float* s_xproj_w = (const float*)d_in[5];
    const float* s_dt_w    = (const float*)d_in[6];
    const float* s_dt_b    = (const float*)d_in[7];
    const float* s_A_log   = (const float*)d_in[8];
    const float* s_D_vec   = (const float*)d_in[9];
    const float* s_out_w   = (const float*)d_in[10];
    const float* c_in_w    = (const float*)d_in[11];
    const float* c_conv_w  = (const float*)d_in[12];
    const float* c_conv_b  = (const float*)d_in[13];
    const float* c_xproj_w = (const float*)d_in[14];
    const float* c_dt_w    = (const float*)d_in[15];
    const float* c_dt_b    = (const float*)d_in[16];
    const float* c_A_log   = (const float*)d_in[17];
    const float* c_D_vec   = (const float*)d_in[18];
    const float* c_out_w   = (const float*)d_in[19];
    const float* ln1_g     = (const float*)d_in[20];
    const float* ln1_b     = (const float*)d_in[21];
    const float* ln2_g     = (const float*)d_in[22];
    const float* ln2_b     = (const float*)d_in[23];
    const float* ln3_g     = (const float*)d_in[24];
    const float* ln3_b     = (const float*)d_in[25];
    const float* ffn_w1    = (const float*)d_in[26];
    const float* ffn_b1    = (const float*)d_in[27];
    const float* ffn_w2    = (const float*)d_in[28];
    const float* ffn_b2    = (const float*)d_in[29];
    float* outp = (float*)d_out;

    // ---- workspace layout ----
    // fp32 region (floats): 11,141,120 floats = 44.6 MB
    float* ws     = (float*)d_ws;
    float* bc     = ws;                     // 393216  (12288 x 32: B|C)
    float* proj   = bc     + 393216;        // 2097152
    float* t1     = proj   + 2097152;       // 2097152
    float* tbuf   = t1     + 2097152;       // 2097152
    float* part_h = tbuf   + 2097152;       // 4194304
    float* part_s = part_h + 4194304;       // 262144
    // bf16 region (ushorts): 81,002,496 elems = 162 MB ; total ~207 MB
    unsigned short* ub      = (unsigned short*)(part_s + 262144);
    unsigned short* dltb    = ub;                   // 12582912 (bf16 delta; ffnout aliases)
    unsigned short* catb    = dltb    + 12582912;   // 6291456
    unsigned short* tgtb    = catb    + 6291456;    // 2097152
    unsigned short* xzb     = tgtb    + 2097152;    // 25165824 (also fbuf alias)
    unsigned short* xcb     = xzb     + 25165824;   // 12582912
    unsigned short* ygb     = xcb     + 12582912;   // 12582912
    unsigned short* tbbf    = ygb     + 12582912;   // 2097152
    unsigned short* s_in_wb = tbbf    + 2097152;    // 1048576  (6-weight block, contiguous)
    unsigned short* c_in_wb = s_in_wb + 1048576;    // 1048576
    unsigned short* s_out_wb= c_in_wb + 1048576;    // 524288
    unsigned short* c_out_wb= s_out_wb+ 524288;     // 524288
    unsigned short* w1b     = c_out_wb+ 524288;     // 1048576
    unsigned short* w2b     = w1b     + 1048576;    // 1048576
    unsigned short* wcomb_s = w2b     + 1048576;    // 1179648 (1152 x 1024)
    unsigned short* wcomb_c = wcomb_s + 1179648;    // 1179648
    unsigned short* fbuf    = xzb;                  // FFN hidden alias
    float* ffnout = (float*)dltb;                   // alias (dltb dead after cross scan)

    // ---- converts & combined-weight fills ----
    f2b_kernel<<<(2097152/4 + 255)/256, 256, 0, stream>>>(tgt, tgtb, 2097152/4);
    mem2catb_kernel<<<(BB*TTM*DM/4 + 255)/256, 256, 0, stream>>>(memory, catb);
    {
        W6 w; w.p[0]=s_in_w; w.p[1]=c_in_w; w.p[2]=s_out_w; w.p[3]=c_out_w; w.p[4]=ffn_w1; w.p[5]=ffn_w2;
        wconv_kernel<<<(1310720 + 255)/256, 256, 0, stream>>>(w, s_in_wb);
    }
    wcomb_kernel<<<(1152*1024)/256, 256, 0, stream>>>(s_dt_w, s_xproj_w, wcomb_s);
    wcomb_kernel<<<(1152*1024)/256, 256, 0, stream>>>(c_dt_w, c_xproj_w, wcomb_c);

    // ---- self mamba (L=512, M=4096) ----
    mgemm_kernel<<<dim3(2048/128, 4096/128), 256, 0, stream>>>(
        tgtb, 4096, 0, 0, s_in_wb, nullptr, nullptr, xzb, nullptr, 2048, 512, ACT_NONE);
    conv_silu_kernel<<<(BB*SS*DI + 255)/256, 256, 0, stream>>>(xzb, s_conv_w, s_conv_b, xcb, SS, BB*SS*DI);
    // combined delta + BC GEMM: M=4096, Ncomb=1152, K=1024
    mgemm_kernel<<<dim3(1152/128, 4096/128), 256, 0, stream>>>(
        xcb, 4096, 0, 0, wcomb_s, s_dt_b, nullptr, dltb, bc, 1152, 1024, ACT_DELTA);
    run_scan(dltb, xcb, bc, xzb, s_A_log, s_D_vec, part_h, part_s, ygb, SS, stream);
    mgemm_kernel<<<dim3(512/128, 4096/128), 256, 0, stream>>>(
        ygb, 4096, 0, 0, s_out_wb, nullptr, proj, nullptr, nullptr, 512, 1024, ACT_NONE);
    // t = LN(tgt + proj): fp32 -> t1, bf16 -> catb rows [b*1536+1024+l]
    addln_kernel<<<4096, 128, 0, stream>>>(
        tgt, 4096, 0, 0, DM, proj, ln1_g, ln1_b,
        t1, 4096, 0, 0, DM, catb, 512, 1536, 1024, DM);

    // ---- cross mamba (L=1536, M=12288) ----
    mgemm_kernel<<<dim3(2048/128, 12288/128), 256, 0, stream>>>(
        catb, 12288, 0, 0, c_in_wb, nullptr, nullptr, xzb, nullptr, 2048, 512, ACT_NONE);
    conv_silu_kernel<<<(BB*LCAT*DI + 255)/256, 256, 0, stream>>>(xzb, c_conv_w, c_conv_b, xcb, LCAT, BB*LCAT*DI);
    mgemm_kernel<<<dim3(1152/128, 12288/128), 256, 0, stream>>>(
        xcb, 12288, 0, 0, wcomb_c, c_dt_b, nullptr, dltb, bc, 1152, 1024, ACT_DELTA);
    run_scan(dltb, xcb, bc, xzb, c_A_log, c_D_vec, part_h, part_s, ygb, LCAT, stream);
    // out proj over last S rows per batch: row(m) = (m/512)*1536 + 1024 + m%512
    mgemm_kernel<<<dim3(512/128, 4096/128), 256, 0, stream>>>(
        ygb, 512, 1536, 1024, c_out_wb, nullptr, proj, nullptr, nullptr, 512, 1024, ACT_NONE);
    addln_kernel<<<4096, 128, 0, stream>>>(
        t1, 4096, 0, 0, DM, proj, ln2_g, ln2_b,
        tbuf, 4096, 0, 0, DM, tbbf, 4096, 0, 0, DM);

    // ---- FFN ----
    mgemm_kernel<<<dim3(2048/128, 4096/128), 256, 0, stream>>>(
        tbbf, 4096, 0, 0, w1b, ffn_b1, nullptr, fbuf, nullptr, 2048, 512, ACT_RELU);
    mgemm_kernel<<<dim3(512/128, 4096/128), 256, 0, stream>>>(
        fbuf, 4096, 0, 0, w2b, ffn_b2, ffnout, nullptr, nullptr, 512, 2048, ACT_NONE);
    addln_kernel<<<4096, 128, 0, stream>>>(
        tbuf, 4096, 0, 0, DM, ffnout, ln3_g, ln3_b,
        outp, 4096, 0, 0, DM, nullptr, 0, 0, 0, 0);
}

// Round 9
// 695.769 us; speedup vs baseline: 1.1718x; 1.0516x over previous
//
#include <hip/hip_runtime.h>
#include <math.h>

// Problem constants
#define DM    512
#define DI    1024
#define DSN   16
#define DTR   32
#define DFFN  2048
#define BB    8
#define SS    512
#define TTM   1024
#define LCAT  1536
#define NC    32      // scan chunks per sequence

#define ACT_NONE     0
#define ACT_RELU     1
#define ACT_DELTA    3   // split epilogue: n<1024 softplus+bias -> Cb(delta bf16); 1024<=n<1056 -> C2(bc fp32)

typedef __attribute__((ext_vector_type(8))) short short8;
typedef __attribute__((ext_vector_type(4))) float f32x4;

__device__ __forceinline__ unsigned short f2b(float f) {
    unsigned int u = __float_as_uint(f);
    return (unsigned short)((u + 0x7FFFu + ((u >> 16) & 1u)) >> 16);
}
__device__ __forceinline__ float b2f(unsigned short h) {
    return __uint_as_float(((unsigned int)h) << 16);
}
__device__ __forceinline__ float fast_softplus(float v) {
    return (v > 20.f) ? v : __logf(1.f + __expf(v));
}
__device__ __forceinline__ void gld16(const void* g, void* l) {
    __builtin_amdgcn_global_load_lds(
        (const __attribute__((address_space(1))) void*)g,
        (__attribute__((address_space(3))) void*)l, 16, 0, 0);
}

__device__ __forceinline__ int map_row(int m, int mb, int bs, int ro) {
    int q = m / mb;
    return q * bs + ro + (m - q * mb);
}

// ================= bf16 MFMA GEMM: C[m,n] = act(A[row(m),k] * W[n,k] + bias[n])
// A: bf16, row stride K. W: bf16, N x K row-major. Tile 128x128, BK=64
// (8 chunks of 16B per row; halves the barrier count vs BK=32 — the K-loop is
// barrier-drain-bound per R8: conflicts 0 and dur unchanged).
// LDS: QUAD-level XOR swizzle. Chunk (row r, k-group g in 0..7) lives at
// position p = r*8 + (g&4) + ((g&3) ^ (r&3)).  Row stride = 128B = full bank
// wrap, so the XOR index must vary EVERY row (r&3), unlike BK=32's (r>>1)&3.
//  - staging: lane L writes pos c = base+L; r=c>>3, q=c&7,
//    g=(q&4)|((q&3)^(r&3)). A quad covers one 64B half-row (XOR permutes
//    within it) -> fully coalesced 64B per quad.
//  - fragment read (half h, lane fm,fg): p = R*8 + h*4 + (fg^(R&3)), R&3=fm&3
//    -> a read quad (4 consecutive fm) hits 4 distinct bank-quads -> conflict-free.
__global__ __launch_bounds__(256) void mgemm_kernel(
    const unsigned short* __restrict__ A, int mb, int bs, int ro,
    const unsigned short* __restrict__ W, const float* __restrict__ bias,
    float* __restrict__ Cf, unsigned short* __restrict__ Cb,
    float* __restrict__ C2,
    int N, int K, int act)
{
    __shared__ __align__(16) unsigned short As[128 * 64];
    __shared__ __align__(16) unsigned short Bs[128 * 64];
    int tid = threadIdx.x;
    int lane = tid & 63, wave = tid >> 6;
    int wy = wave >> 1, wx = wave & 1;
    // XCD-band swizzle (gridDim.y assumed divisible by 8)
    int nx = gridDim.x;
    int f = blockIdx.y * nx + blockIdx.x;
    int xcd = f & 7, j2 = f >> 3;
    int bandh = gridDim.y >> 3;
    int m0 = (xcd * bandh + j2 / nx) * 128;
    int n0 = (j2 % nx) * 128;

    // staging: wave stages chunk positions c = wave*256 + j*64 + lane (j=0..3)
    const unsigned short* ga[4];
    const unsigned short* gb[4];
    unsigned short* la[4];
    unsigned short* lb[4];
    #pragma unroll
    for (int j = 0; j < 4; j++) {
        int c  = wave * 256 + j * 64 + lane;
        int r  = c >> 3;                    // tile row 0..127
        int q  = c & 7;
        int g  = (q & 4) | ((q & 3) ^ (r & 3));   // un-swizzled k-chunk 0..7
        int arow = map_row(m0 + r, mb, bs, ro);
        ga[j] = A + (size_t)arow * K + g * 8;
        gb[j] = W + (size_t)(n0 + r) * K + g * 8;
        la[j] = As + (size_t)(wave * 256 + j * 64) * 8;   // chunk pos * 8 shorts
        lb[j] = Bs + (size_t)(wave * 256 + j * 64) * 8;
    }
    // fragment read bases (swizzled); R&3 == fm&3 (t*16, wy*64 are mult of 4)
    int fm = lane & 15, fg = lane >> 4;
    int sw = fg ^ (fm & 3);
    const unsigned short* arp = As + ((size_t)(wy * 64 + fm) * 8 + sw) * 8;
    const unsigned short* brp = Bs + ((size_t)(wx * 64 + fm) * 8 + sw) * 8;

    f32x4 acc[4][4];
    #pragma unroll
    for (int i = 0; i < 4; i++)
        #pragma unroll
        for (int j = 0; j < 4; j++) acc[i][j] = 0.f;

    for (int k0 = 0; k0 < K; k0 += 64) {
        #pragma unroll
        for (int j = 0; j < 4; j++) {
            gld16(ga[j] + k0, la[j]);
            gld16(gb[j] + k0, lb[j]);
        }
        __syncthreads();
        #pragma unroll
        for (int h = 0; h < 2; h++) {
            short8 af[4], bfr[4];
            #pragma unroll
            for (int t = 0; t < 4; t++) af[t]  = *(const short8*)(arp + h * 32 + t * 1024);
            #pragma unroll
            for (int t = 0; t < 4; t++) bfr[t] = *(const short8*)(brp + h * 32 + t * 1024);
            #pragma unroll
            for (int i = 0; i < 4; i++)
                #pragma unroll
                for (int j = 0; j < 4; j++)
                    acc[i][j] = __builtin_amdgcn_mfma_f32_16x16x32_bf16(af[i], bfr[j], acc[i][j], 0, 0, 0);
        }
        __syncthreads();
    }

    // epilogue: C/D layout col=lane&15 (n), row=(lane>>4)*4+reg (m)
    int en = lane & 15, em = (lane >> 4) * 4;
    if (act == ACT_DELTA) {
        #pragma unroll
        for (int j = 0; j < 4; j++) {
            int n = n0 + wx * 64 + j * 16 + en;
            bool is_delta = (n < 1024);
            if (!is_delta && n >= 1056) continue;
            float bv = is_delta ? bias[n] : 0.f;
            #pragma unroll
            for (int i = 0; i < 4; i++) {
                int mbase = m0 + wy * 64 + i * 16 + em;
                #pragma unroll
                for (int r = 0; r < 4; r++) {
                    float v = acc[i][j][r] + bv;
                    if (is_delta) {
                        Cb[(size_t)(mbase + r) * 1024 + n] = f2b(fast_softplus(v));
                    } else {
                        C2[(size_t)(mbase + r) * 32 + (n - 1024)] = v;
                    }
                }
            }
        }
        return;
    }
    #pragma unroll
    for (int j = 0; j < 4; j++) {
        int n = n0 + wx * 64 + j * 16 + en;
        float bv = bias ? bias[n] : 0.f;
        #pragma unroll
        for (int i = 0; i < 4; i++) {
            int mbase = m0 + wy * 64 + i * 16 + em;
            #pragma unroll
            for (int r = 0; r < 4; r++) {
                float v = acc[i][j][r] + bv;
                if (act == ACT_RELU) v = v > 0.f ? v : 0.f;
                size_t off = (size_t)(mbase + r) * N + n;
                if (Cb) Cb[off] = f2b(v);
                else    Cf[off] = v;
            }
        }
    }
}

// ================= Wcomb fill: rows 0..1023 = dt_w @ xproj[:32]; 1024..1055 = xproj rows 32..63; rest 0
__global__ void wcomb_kernel(const float* __restrict__ dt_w,
                             const float* __restrict__ xproj,
                             unsigned short* __restrict__ out)
{
    int idx = blockIdx.x * 256 + threadIdx.x;   // n*1024 + k, n < 1152
    int n = idx >> 10, k = idx & 1023;
    float v = 0.f;
    if (n < 1024) {
        #pragma unroll
        for (int r = 0; r < DTR; r++)
            v = fmaf(dt_w[n * DTR + r], xproj[r * 1024 + k], v);
    } else if (n < 1056) {
        v = xproj[(n - 1024 + 32) * 1024 + k];
    }
    out[idx] = f2b(v);
}

// ================= Depthwise causal conv (width 4) + bias + SiLU. bf16 in, bf16 out.
__global__ void conv_silu_kernel(const unsigned short* __restrict__ xz,
                                 const float* __restrict__ cw,
                                 const float* __restrict__ cb,
                                 unsigned short* __restrict__ xc, int L, int total)
{
    int idx = blockIdx.x * blockDim.x + threadIdx.x;
    if (idx >= total) return;
    int d = idx & (DI - 1);
    int r = idx >> 10;     // b*L + l
    int l = r % L;
    float acc = cb[d];
    #pragma unroll
    for (int k = 0; k < 4; k++) {
        int ls = l - 3 + k;
        if (ls >= 0) acc = fmaf(b2f(xz[(size_t)(r - 3 + k) * 2048 + d]), cw[d * 4 + k], acc);
    }
    float s = acc / (1.f + __expf(-acc));
    xc[idx] = f2b(s);
}

// ================= Chunked selective scan (delta bf16)
__global__ __launch_bounds__(256) void scan_part1(
    const unsigned short* __restrict__ delta, const unsigned short* __restrict__ xc,
    const float* __restrict__ bc, const float* __restrict__ A_log,
    float* __restrict__ part_h, float* __restrict__ part_s, int L, int CH)
{
    int tid = threadIdx.x;
    int dblk = blockIdx.x & 3;
    int c    = (blockIdx.x >> 2) & (NC - 1);
    int b    = blockIdx.x >> 7;
    int d    = dblk * 256 + tid;
    float A[DSN];
    #pragma unroll
    for (int s = 0; s < DSN; s++) A[s] = -__expf(A_log[d * DSN + s]);
    float h[DSN];
    #pragma unroll
    for (int s = 0; s < DSN; s++) h[s] = 0.f;
    float ssum = 0.f;
    int l0 = c * CH;
    for (int l = l0; l < l0 + CH; l++) {
        size_t r = (size_t)b * L + l;
        float4 bq[4];
        const float4* bp = (const float4*)(bc + r * 32);
        #pragma unroll
        for (int q = 0; q < 4; q++) bq[q] = bp[q];
        const float* Bm = (const float*)&bq[0];
        float dl = b2f(delta[r * DI + d]);
        float u  = b2f(xc[r * DI + d]);
        float du = dl * u;
        ssum += dl;
        #pragma unroll
        for (int s = 0; s < DSN; s++)
            h[s] = fmaf(__expf(dl * A[s]), h[s], du * Bm[s]);
    }
    size_t base = ((size_t)(b * NC + c) * DI + d) * DSN;
    #pragma unroll
    for (int q = 0; q < 4; q++)
        ((float4*)(part_h + base))[q] = make_float4(h[q*4], h[q*4+1], h[q*4+2], h[q*4+3]);
    part_s[(size_t)(b * NC + c) * DI + d] = ssum;
}

__global__ __launch_bounds__(256) void scan_combine(
    const float* __restrict__ A_log,
    float* __restrict__ part_h, const float* __restrict__ part_s)
{
    int idx = blockIdx.x * 256 + threadIdx.x;
    int b = idx >> 10, d = idx & (DI - 1);
    float A[DSN];
    #pragma unroll
    for (int s = 0; s < DSN; s++) A[s] = -__expf(A_log[d * DSN + s]);
    float h[DSN];
    #pragma unroll
    for (int s = 0; s < DSN; s++) h[s] = 0.f;
    for (int c = 0; c < NC; c++) {
        size_t base = ((size_t)(b * NC + c) * DI + d) * DSN;
        float4 ph4[4];
        #pragma unroll
        for (int q = 0; q < 4; q++) ph4[q] = ((const float4*)(part_h + base))[q];
        const float* ph = (const float*)&ph4[0];
        float S = part_s[(size_t)(b * NC + c) * DI + d];
        #pragma unroll
        for (int q = 0; q < 4; q++)
            ((float4*)(part_h + base))[q] = make_float4(h[q*4], h[q*4+1], h[q*4+2], h[q*4+3]);
        #pragma unroll
        for (int s = 0; s < DSN; s++)
            h[s] = fmaf(__expf(A[s] * S), h[s], ph[s]);
    }
}

// pass 3: rescan chunk from h_in, emit gated output to bf16 buffer.
__global__ __launch_bounds__(256) void scan_part2(
    const unsigned short* __restrict__ delta, const unsigned short* __restrict__ xc,
    const float* __restrict__ bc, const unsigned short* __restrict__ xz,
    const float* __restrict__ A_log, const float* __restrict__ Dv,
    const float* __restrict__ part_h,
    unsigned short* __restrict__ out, int L, int CH)
{
    int tid = threadIdx.x;
    int dblk = blockIdx.x & 3;
    int c    = (blockIdx.x >> 2) & (NC - 1);
    int b    = blockIdx.x >> 7;
    int d    = dblk * 256 + tid;
    float A[DSN];
    #pragma unroll
    for (int s = 0; s < DSN; s++) A[s] = -__expf(A_log[d * DSN + s]);
    float Dvd = Dv[d];
    size_t base = ((size_t)(b * NC + c) * DI + d) * DSN;
    float h4[4][4];
    #pragma unroll
    for (int q = 0; q < 4; q++) *((float4*)h4[q]) = ((const float4*)(part_h + base))[q];
    float h[DSN];
    #pragma unroll
    for (int s = 0; s < DSN; s++) h[s] = h4[s >> 2][s & 3];
    int l0 = c * CH;
    for (int l = l0; l < l0 + CH; l++) {
        size_t r = (size_t)b * L + l;
        float4 bq[8];
        const float4* bp = (const float4*)(bc + r * 32);
        #pragma unroll
        for (int q = 0; q < 8; q++) bq[q] = bp[q];
        const float* Bm = (const float*)&bq[0];
        const float* Cm = Bm + DSN;
        float dl = b2f(delta[r * DI + d]);
        float u  = b2f(xc[r * DI + d]);
        float du = dl * u;
        float y = 0.f;
        #pragma unroll
        for (int s = 0; s < DSN; s++) {
            h[s] = fmaf(__expf(dl * A[s]), h[s], du * Bm[s]);
            y = fmaf(h[s], Cm[s], y);
        }
        float z = b2f(xz[r * 2048 + DI + d]);
        float sil = z / (1.f + __expf(-z));
        out[r * DI + d] = f2b((y + u * Dvd) * sil);
    }
}

// ================= residual add + LayerNorm; optional fp32 and bf16 outputs
__global__ __launch_bounds__(128) void addln_kernel(
    const float* __restrict__ a, int amb, int absd, int aro, int lda,
    const float* __restrict__ bsrc,
    const float* __restrict__ g, const float* __restrict__ be,
    float* __restrict__ outf, int omb, int obsd, int oro, int ldo,
    unsigned short* __restrict__ outb, int bmb, int bbsd, int bro, int ldb)
{
    int m = blockIdx.x, t = threadIdx.x;
    int ar = map_row(m, amb, absd, aro);
    float4 x4 = ((const float4*)(a + (size_t)ar * lda))[t];
    float4 y4 = ((const float4*)(bsrc + (size_t)m * DM))[t];
    float v[4] = {x4.x + y4.x, x4.y + y4.y, x4.z + y4.z, x4.w + y4.w};
    float sum = v[0] + v[1] + v[2] + v[3];
    float sq  = v[0]*v[0] + v[1]*v[1] + v[2]*v[2] + v[3]*v[3];
    #pragma unroll
    for (int o = 32; o > 0; o >>= 1) {
        sum += __shfl_down(sum, o);
        sq  += __shfl_down(sq, o);
    }
    __shared__ float s0[2], s1[2];
    if ((t & 63) == 0) { s0[t >> 6] = sum; s1[t >> 6] = sq; }
    __syncthreads();
    float tot = s0[0] + s0[1];
    float tsq = s1[0] + s1[1];
    float mu = tot * (1.f / DM);
    float var = tsq * (1.f / DM) - mu * mu;
    float rs = rsqrtf(var + 1e-6f);
    float4 g4 = ((const float4*)g)[t];
    float4 b4 = ((const float4*)be)[t];
    float o0 = (v[0] - mu) * rs * g4.x + b4.x;
    float o1 = (v[1] - mu) * rs * g4.y + b4.y;
    float o2 = (v[2] - mu) * rs * g4.z + b4.z;
    float o3 = (v[3] - mu) * rs * g4.w + b4.w;
    if (outf) {
        int orow = map_row(m, omb, obsd, oro);
        ((float4*)(outf + (size_t)orow * ldo))[t] = make_float4(o0, o1, o2, o3);
    }
    if (outb) {
        int brow = map_row(m, bmb, bbsd, bro);
        ((ushort4*)(outb + (size_t)brow * ldb))[t] =
            make_ushort4(f2b(o0), f2b(o1), f2b(o2), f2b(o3));
    }
}

// ================= fp32 -> bf16 convert (n4 float4 groups)
__global__ void f2b_kernel(const float* __restrict__ in, unsigned short* __restrict__ out, int n4)
{
    int i = blockIdx.x * 256 + threadIdx.x;
    if (i >= n4) return;
    float4 v = ((const float4*)in)[i];
    ((ushort4*)out)[i] = make_ushort4(f2b(v.x), f2b(v.y), f2b(v.z), f2b(v.w));
}

// ================= merged 6-weight fp32 -> bf16 convert (contiguous bf16 output region)
struct W6 { const float* p[6]; };
__global__ void wconv_kernel(W6 w, unsigned short* __restrict__ out)
{
    const int cum[7] = {0, 262144, 524288, 655360, 786432, 1048576, 1310720};
    int i = blockIdx.x * 256 + threadIdx.x;
    if (i >= 1310720) return;
    int seg = 0;
    #pragma unroll
    for (int s = 1; s < 6; s++) seg += (i >= cum[s]);
    float4 v = ((const float4*)w.p[seg])[i - cum[seg]];
    ((ushort4*)out)[i] = make_ushort4(f2b(v.x), f2b(v.y), f2b(v.z), f2b(v.w));
}

// ================= memory(fp32) -> catb(bf16) rows [b*1536 + 0..1023]
__global__ void mem2catb_kernel(const float* __restrict__ mem, unsigned short* __restrict__ catb)
{
    int f = blockIdx.x * blockDim.x + threadIdx.x;
    const int total = BB * TTM * DM / 4;
    if (f >= total) return;
    const int per_b = TTM * DM / 4;
    int b = f / per_b, rem = f - b * per_b;
    float4 v = ((const float4*)mem)[f];
    ((ushort4*)catb)[(size_t)b * (LCAT * DM / 4) + rem] =
        make_ushort4(f2b(v.x), f2b(v.y), f2b(v.z), f2b(v.w));
}

static void run_scan(const unsigned short* dltb, const unsigned short* xcb, const float* bc,
                     const unsigned short* xzb, const float* A_log, const float* Dv,
                     float* part_h, float* part_s, unsigned short* out, int L,
                     hipStream_t stream)
{
    int CH = L / NC;
    int blocks = BB * NC * (DI / 256);
    scan_part1<<<blocks, 256, 0, stream>>>(dltb, xcb, bc, A_log, part_h, part_s, L, CH);
    scan_combine<<<BB * DI / 256, 256, 0, stream>>>(A_log, part_h, part_s);
    scan_part2<<<blocks, 256, 0, stream>>>(dltb, xcb, bc, xzb, A_log, Dv, part_h, out, L, CH);
}

extern "C" void kernel_launch(void* const* d_in, const int* in_sizes, int n_in,
                              void* d_out, int out_size, void* d_ws, size_t ws_size,
                              hipStream_t stream)
{
    const float* tgt       = (const float*)d_in[0];
    const float* memory    = (const float*)d_in[1];
    const float* s_in_w    = (const float*)d_in[2];
    const float* s_conv_w  = (const float*)d_in[3];
    const float* s_conv_b  = (const float*)d_in[4];
    const float* s_xproj_w = (const float*)d_in[5];
    const float* s_dt_w    = (const float*)d_in[6];
    const float* s_dt_b    = (const float*)d_in[7];
    const float* s_A_log   = (const float*)d_in[8];
    const float* s_D_vec   = (const float*)d_in[9];
    const float* s_out_w   = (const float*)d_in[10];
    const float* c_in_w    = (const float*)d_in[11];
    const float* c_conv_w  = (const float*)d_in[12];
    const float* c_conv_b  = (const float*)d_in[13];
    const float* c_xproj_w = (const float*)d_in[14];
    const float* c_dt_w    = (const float*)d_in[15];
    const float* c_dt_b    = (const float*)d_in[16];
    const float* c_A_log   = (const float*)d_in[17];
    const float* c_D_vec   = (const float*)d_in[18];
    const float* c_out_w   = (const float*)d_in[19];
    const float* ln1_g     = (const float*)d_in[20];
    const float* ln1_b     = (const float*)d_in[21];
    const float* ln2_g     = (const float*)d_in[22];
    const float* ln2_b     = (const float*)d_in[23];
    const float* ln3_g     = (const float*)d_in[24];
    const float* ln3_b     = (const float*)d_in[25];
    const float* ffn_w1    = (const float*)d_in[26];
    const float* ffn_b1    = (const float*)d_in[27];
    const float* ffn_w2    = (const float*)d_in[28];
    const float* ffn_b2    = (const float*)d_in[29];
    float* outp = (float*)d_out;

    // ---- workspace layout ----
    // fp32 region (floats): 11,141,120 floats = 44.6 MB
    float* ws     = (float*)d_ws;
    float* bc     = ws;                     // 393216  (12288 x 32: B|C)
    float* proj   = bc     + 393216;        // 2097152
    float* t1     = proj   + 2097152;       // 2097152
    float* tbuf   = t1     + 2097152;       // 2097152
    float* part_h = tbuf   + 2097152;       // 4194304
    float* part_s = part_h + 4194304;       // 262144
    // bf16 region (ushorts): 81,002,496 elems = 162 MB ; total ~207 MB
    unsigned short* ub      = (unsigned short*)(part_s + 262144);
    unsigned short* dltb    = ub;                   // 12582912 (bf16 delta; ffnout aliases)
    unsigned short* catb    = dltb    + 12582912;   // 6291456
    unsigned short* tgtb    = catb    + 6291456;    // 2097152
    unsigned short* xzb     = tgtb    + 2097152;    // 25165824 (also fbuf alias)
    unsigned short* xcb     = xzb     + 25165824;   // 12582912
    unsigned short* ygb     = xcb     + 12582912;   // 12582912
    unsigned short* tbbf    = ygb     + 12582912;   // 2097152
    unsigned short* s_in_wb = tbbf    + 2097152;    // 1048576  (6-weight block, contiguous)
    unsigned short* c_in_wb = s_in_wb + 1048576;    // 1048576
    unsigned short* s_out_wb= c_in_wb + 1048576;    // 524288
    unsigned short* c_out_wb= s_out_wb+ 524288;     // 524288
    unsigned short* w1b     = c_out_wb+ 524288;     // 1048576
    unsigned short* w2b     = w1b     + 1048576;    // 1048576
    unsigned short* wcomb_s = w2b     + 1048576;    // 1179648 (1152 x 1024)
    unsigned short* wcomb_c = wcomb_s + 1179648;    // 1179648
    unsigned short* fbuf    = xzb;                  // FFN hidden alias
    float* ffnout = (float*)dltb;                   // alias (dltb dead after cross scan)

    // ---- converts & combined-weight fills ----
    f2b_kernel<<<(2097152/4 + 255)/256, 256, 0, stream>>>(tgt, tgtb, 2097152/4);
    mem2catb_kernel<<<(BB*TTM*DM/4 + 255)/256, 256, 0, stream>>>(memory, catb);
    {
        W6 w; w.p[0]=s_in_w; w.p[1]=c_in_w; w.p[2]=s_out_w; w.p[3]=c_out_w; w.p[4]=ffn_w1; w.p[5]=ffn_w2;
        wconv_kernel<<<(1310720 + 255)/256, 256, 0, stream>>>(w, s_in_wb);
    }
    wcomb_kernel<<<(1152*1024)/256, 256, 0, stream>>>(s_dt_w, s_xproj_w, wcomb_s);
    wcomb_kernel<<<(1152*1024)/256, 256, 0, stream>>>(c_dt_w, c_xproj_w, wcomb_c);

    // ---- self mamba (L=512, M=4096) ----
    mgemm_kernel<<<dim3(2048/128, 4096/128), 256, 0, stream>>>(
        tgtb, 4096, 0, 0, s_in_wb, nullptr, nullptr, xzb, nullptr, 2048, 512, ACT_NONE);
    conv_silu_kernel<<<(BB*SS*DI + 255)/256, 256, 0, stream>>>(xzb, s_conv_w, s_conv_b, xcb, SS, BB*SS*DI);
    // combined delta + BC GEMM: M=4096, Ncomb=1152, K=1024
    mgemm_kernel<<<dim3(1152/128, 4096/128), 256, 0, stream>>>(
        xcb, 4096, 0, 0, wcomb_s, s_dt_b, nullptr, dltb, bc, 1152, 1024, ACT_DELTA);
    run_scan(dltb, xcb, bc, xzb, s_A_log, s_D_vec, part_h, part_s, ygb, SS, stream);
    mgemm_kernel<<<dim3(512/128, 4096/128), 256, 0, stream>>>(
        ygb, 4096, 0, 0, s_out_wb, nullptr, proj, nullptr, nullptr, 512, 1024, ACT_NONE);
    // t = LN(tgt + proj): fp32 -> t1, bf16 -> catb rows [b*1536+1024+l]
    addln_kernel<<<4096, 128, 0, stream>>>(
        tgt, 4096, 0, 0, DM, proj, ln1_g, ln1_b,
        t1, 4096, 0, 0, DM, catb, 512, 1536, 1024, DM);

    // ---- cross mamba (L=1536, M=12288) ----
    mgemm_kernel<<<dim3(2048/128, 12288/128), 256, 0, stream>>>(
        catb, 12288, 0, 0, c_in_wb, nullptr, nullptr, xzb, nullptr, 2048, 512, ACT_NONE);
    conv_silu_kernel<<<(BB*LCAT*DI + 255)/256, 256, 0, stream>>>(xzb, c_conv_w, c_conv_b, xcb, LCAT, BB*LCAT*DI);
    mgemm_kernel<<<dim3(1152/128, 12288/128), 256, 0, stream>>>(
        xcb, 12288, 0, 0, wcomb_c, c_dt_b, nullptr, dltb, bc, 1152, 1024, ACT_DELTA);
    run_scan(dltb, xcb, bc, xzb, c_A_log, c_D_vec, part_h, part_s, ygb, LCAT, stream);
    // out proj over last S rows per batch: row(m) = (m/512)*1536 + 1024 + m%512
    mgemm_kernel<<<dim3(512/128, 4096/128), 256, 0, stream>>>(
        ygb, 512, 1536, 1024, c_out_wb, nullptr, proj, nullptr, nullptr, 512, 1024, ACT_NONE);
    addln_kernel<<<4096, 128, 0, stream>>>(
        t1, 4096, 0, 0, DM, proj, ln2_g, ln2_b,
        tbuf, 4096, 0, 0, DM, tbbf, 4096, 0, 0, DM);

    // ---- FFN ----
    mgemm_kernel<<<dim3(2048/128, 4096/128), 256, 0, stream>>>(
        tbbf, 4096, 0, 0, w1b, ffn_b1, nullptr, fbuf, nullptr, 2048, 512, ACT_RELU);
    mgemm_kernel<<<dim3(512/128, 4096/128), 256, 0, stream>>>(
        fbuf, 4096, 0, 0, w2b, ffn_b2, ffnout, nullptr, nullptr, 512, 2048, ACT_NONE);
    addln_kernel<<<4096, 128, 0, stream>>>(
        tbuf, 4096, 0, 0, DM, ffnout, ln3_g, ln3_b,
        outp, 4096, 0, 0, DM, nullptr, 0, 0, 0, 0);
}

// Round 10
// 686.048 us; speedup vs baseline: 1.1884x; 1.0142x over previous
//
#include <hip/hip_runtime.h>
#include <math.h>

// Problem constants
#define DM    512
#define DI    1024
#define DSN   16
#define DTR   32
#define DFFN  2048
#define BB    8
#define SS    512
#define TTM   1024
#define LCAT  1536
#define NC    32      // scan chunks per sequence

#define ACT_NONE     0
#define ACT_RELU     1
#define ACT_DELTA    3   // split epilogue: n<1024 softplus+bias -> Cb(delta bf16); 1024<=n<1056 -> C2(bc fp32)

typedef __attribute__((ext_vector_type(8))) short short8;
typedef __attribute__((ext_vector_type(8))) unsigned short ushort8;
typedef __attribute__((ext_vector_type(4))) float f32x4;

__device__ __forceinline__ unsigned short f2b(float f) {
    unsigned int u = __float_as_uint(f);
    return (unsigned short)((u + 0x7FFFu + ((u >> 16) & 1u)) >> 16);
}
__device__ __forceinline__ float b2f(unsigned short h) {
    return __uint_as_float(((unsigned int)h) << 16);
}
__device__ __forceinline__ float fast_softplus(float v) {
    return (v > 20.f) ? v : __logf(1.f + __expf(v));
}
__device__ __forceinline__ void gld16(const void* g, void* l) {
    __builtin_amdgcn_global_load_lds(
        (const __attribute__((address_space(1))) void*)g,
        (__attribute__((address_space(3))) void*)l, 16, 0, 0);
}

__device__ __forceinline__ int map_row(int m, int mb, int bs, int ro) {
    int q = m / mb;
    return q * bs + ro + (m - q * mb);
}

// ================= bf16 MFMA GEMM: C[m,n] = act(A[row(m),k] * W[n,k] + bias[n])
// A: bf16, row stride K. W: bf16, N x K row-major. Tile 128x128, BK=64.
// LDS: QUAD-level XOR swizzle (see R7/R8 notes). Chunk (row r, k-group g in
// 0..7) lives at position p = r*8 + (g&4) + ((g&3) ^ (r&3)).
__global__ __launch_bounds__(256) void mgemm_kernel(
    const unsigned short* __restrict__ A, int mb, int bs, int ro,
    const unsigned short* __restrict__ W, const float* __restrict__ bias,
    float* __restrict__ Cf, unsigned short* __restrict__ Cb,
    float* __restrict__ C2,
    int N, int K, int act)
{
    __shared__ __align__(16) unsigned short As[128 * 64];
    __shared__ __align__(16) unsigned short Bs[128 * 64];
    int tid = threadIdx.x;
    int lane = tid & 63, wave = tid >> 6;
    int wy = wave >> 1, wx = wave & 1;
    // XCD-band swizzle (gridDim.y assumed divisible by 8)
    int nx = gridDim.x;
    int f = blockIdx.y * nx + blockIdx.x;
    int xcd = f & 7, j2 = f >> 3;
    int bandh = gridDim.y >> 3;
    int m0 = (xcd * bandh + j2 / nx) * 128;
    int n0 = (j2 % nx) * 128;

    // staging: wave stages chunk positions c = wave*256 + j*64 + lane (j=0..3)
    const unsigned short* ga[4];
    const unsigned short* gb[4];
    unsigned short* la[4];
    unsigned short* lb[4];
    #pragma unroll
    for (int j = 0; j < 4; j++) {
        int c  = wave * 256 + j * 64 + lane;
        int r  = c >> 3;                    // tile row 0..127
        int q  = c & 7;
        int g  = (q & 4) | ((q & 3) ^ (r & 3));   // un-swizzled k-chunk 0..7
        int arow = map_row(m0 + r, mb, bs, ro);
        ga[j] = A + (size_t)arow * K + g * 8;
        gb[j] = W + (size_t)(n0 + r) * K + g * 8;
        la[j] = As + (size_t)(wave * 256 + j * 64) * 8;   // chunk pos * 8 shorts
        lb[j] = Bs + (size_t)(wave * 256 + j * 64) * 8;
    }
    // fragment read bases (swizzled); R&3 == fm&3 (t*16, wy*64 are mult of 4)
    int fm = lane & 15, fg = lane >> 4;
    int sw = fg ^ (fm & 3);
    const unsigned short* arp = As + ((size_t)(wy * 64 + fm) * 8 + sw) * 8;
    const unsigned short* brp = Bs + ((size_t)(wx * 64 + fm) * 8 + sw) * 8;

    f32x4 acc[4][4];
    #pragma unroll
    for (int i = 0; i < 4; i++)
        #pragma unroll
        for (int j = 0; j < 4; j++) acc[i][j] = 0.f;

    for (int k0 = 0; k0 < K; k0 += 64) {
        #pragma unroll
        for (int j = 0; j < 4; j++) {
            gld16(ga[j] + k0, la[j]);
            gld16(gb[j] + k0, lb[j]);
        }
        __syncthreads();
        #pragma unroll
        for (int h = 0; h < 2; h++) {
            short8 af[4], bfr[4];
            #pragma unroll
            for (int t = 0; t < 4; t++) af[t]  = *(const short8*)(arp + h * 32 + t * 1024);
            #pragma unroll
            for (int t = 0; t < 4; t++) bfr[t] = *(const short8*)(brp + h * 32 + t * 1024);
            #pragma unroll
            for (int i = 0; i < 4; i++)
                #pragma unroll
                for (int j = 0; j < 4; j++)
                    acc[i][j] = __builtin_amdgcn_mfma_f32_16x16x32_bf16(af[i], bfr[j], acc[i][j], 0, 0, 0);
        }
        __syncthreads();
    }

    // epilogue: C/D layout col=lane&15 (n), row=(lane>>4)*4+reg (m)
    int en = lane & 15, em = (lane >> 4) * 4;
    if (act == ACT_DELTA) {
        #pragma unroll
        for (int j = 0; j < 4; j++) {
            int n = n0 + wx * 64 + j * 16 + en;
            bool is_delta = (n < 1024);
            if (!is_delta && n >= 1056) continue;
            float bv = is_delta ? bias[n] : 0.f;
            #pragma unroll
            for (int i = 0; i < 4; i++) {
                int mbase = m0 + wy * 64 + i * 16 + em;
                #pragma unroll
                for (int r = 0; r < 4; r++) {
                    float v = acc[i][j][r] + bv;
                    if (is_delta) {
                        Cb[(size_t)(mbase + r) * 1024 + n] = f2b(fast_softplus(v));
                    } else {
                        C2[(size_t)(mbase + r) * 32 + (n - 1024)] = v;
                    }
                }
            }
        }
        return;
    }
    #pragma unroll
    for (int j = 0; j < 4; j++) {
        int n = n0 + wx * 64 + j * 16 + en;
        float bv = bias ? bias[n] : 0.f;
        #pragma unroll
        for (int i = 0; i < 4; i++) {
            int mbase = m0 + wy * 64 + i * 16 + em;
            #pragma unroll
            for (int r = 0; r < 4; r++) {
                float v = acc[i][j][r] + bv;
                if (act == ACT_RELU) v = v > 0.f ? v : 0.f;
                size_t off = (size_t)(mbase + r) * N + n;
                if (Cb) Cb[off] = f2b(v);
                else    Cf[off] = v;
            }
        }
    }
}

// ================= Wcomb fill: rows 0..1023 = dt_w @ xproj[:32]; 1024..1055 = xproj rows 32..63; rest 0
__global__ void wcomb_kernel(const float* __restrict__ dt_w,
                             const float* __restrict__ xproj,
                             unsigned short* __restrict__ out)
{
    int idx = blockIdx.x * 256 + threadIdx.x;   // n*1024 + k, n < 1152
    int n = idx >> 10, k = idx & 1023;
    float v = 0.f;
    if (n < 1024) {
        #pragma unroll
        for (int r = 0; r < DTR; r++)
            v = fmaf(dt_w[n * DTR + r], xproj[r * 1024 + k], v);
    } else if (n < 1056) {
        v = xproj[(n - 1024 + 32) * 1024 + k];
    }
    out[idx] = f2b(v);
}

// ================= Depthwise causal conv (width 4) + bias + SiLU.
// Vectorized: one thread per 8 consecutive channels (ushort8 = 16B/lane).
// 4x 16B row loads (causally guarded) + 1x 16B store -> 1KB/wave coalesced.
__global__ __launch_bounds__(256) void conv_silu_kernel(
    const unsigned short* __restrict__ xz,
    const float* __restrict__ cw,
    const float* __restrict__ cb,
    unsigned short* __restrict__ xc, int L, int total8)
{
    int idx = blockIdx.x * blockDim.x + threadIdx.x;
    if (idx >= total8) return;
    int d8 = idx & 127;            // channel group (1024/8 = 128 per row)
    int d0 = d8 * 8;
    int r  = idx >> 7;             // b*L + l
    int l  = r % L;
    float acc[8];
    {
        float4 c0 = ((const float4*)(cb + d0))[0];
        float4 c1 = ((const float4*)(cb + d0))[1];
        acc[0]=c0.x; acc[1]=c0.y; acc[2]=c0.z; acc[3]=c0.w;
        acc[4]=c1.x; acc[5]=c1.y; acc[6]=c1.z; acc[7]=c1.w;
    }
    // weights: cw[(d0+j)*4 + k] -> 8 float4 (one per channel)
    float4 wv[8];
    #pragma unroll
    for (int j = 0; j < 8; j++) wv[j] = *(const float4*)(cw + (d0 + j) * 4);
    #pragma unroll
    for (int k = 0; k < 4; k++) {
        int ls = l - 3 + k;
        if (ls >= 0) {
            ushort8 v = *(const ushort8*)(xz + (size_t)(r - 3 + k) * 2048 + d0);
            const float* w = (const float*)&wv[0];
            #pragma unroll
            for (int j = 0; j < 8; j++)
                acc[j] = fmaf(b2f(v[j]), w[j * 4 + k], acc[j]);
        }
    }
    ushort8 o;
    #pragma unroll
    for (int j = 0; j < 8; j++) {
        float s = acc[j] / (1.f + __expf(-acc[j]));
        o[j] = f2b(s);
    }
    *(ushort8*)(xc + (size_t)r * 1024 + d0) = o;
}

// ================= Chunked selective scan (delta bf16)
__global__ __launch_bounds__(256) void scan_part1(
    const unsigned short* __restrict__ delta, const unsigned short* __restrict__ xc,
    const float* __restrict__ bc, const float* __restrict__ A_log,
    float* __restrict__ part_h, float* __restrict__ part_s, int L, int CH)
{
    int tid = threadIdx.x;
    int dblk = blockIdx.x & 3;
    int c    = (blockIdx.x >> 2) & (NC - 1);
    int b    = blockIdx.x >> 7;
    int d    = dblk * 256 + tid;
    float A[DSN];
    #pragma unroll
    for (int s = 0; s < DSN; s++) A[s] = -__expf(A_log[d * DSN + s]);
    float h[DSN];
    #pragma unroll
    for (int s = 0; s < DSN; s++) h[s] = 0.f;
    float ssum = 0.f;
    int l0 = c * CH;
    for (int l = l0; l < l0 + CH; l++) {
        size_t r = (size_t)b * L + l;
        float4 bq[4];
        const float4* bp = (const float4*)(bc + r * 32);
        #pragma unroll
        for (int q = 0; q < 4; q++) bq[q] = bp[q];
        const float* Bm = (const float*)&bq[0];
        float dl = b2f(delta[r * DI + d]);
        float u  = b2f(xc[r * DI + d]);
        float du = dl * u;
        ssum += dl;
        #pragma unroll
        for (int s = 0; s < DSN; s++)
            h[s] = fmaf(__expf(dl * A[s]), h[s], du * Bm[s]);
    }
    size_t base = ((size_t)(b * NC + c) * DI + d) * DSN;
    #pragma unroll
    for (int q = 0; q < 4; q++)
        ((float4*)(part_h + base))[q] = make_float4(h[q*4], h[q*4+1], h[q*4+2], h[q*4+3]);
    part_s[(size_t)(b * NC + c) * DI + d] = ssum;
}

__global__ __launch_bounds__(256) void scan_combine(
    const float* __restrict__ A_log,
    float* __restrict__ part_h, const float* __restrict__ part_s)
{
    int idx = blockIdx.x * 256 + threadIdx.x;
    int b = idx >> 10, d = idx & (DI - 1);
    float A[DSN];
    #pragma unroll
    for (int s = 0; s < DSN; s++) A[s] = -__expf(A_log[d * DSN + s]);
    float h[DSN];
    #pragma unroll
    for (int s = 0; s < DSN; s++) h[s] = 0.f;
    for (int c = 0; c < NC; c++) {
        size_t base = ((size_t)(b * NC + c) * DI + d) * DSN;
        float4 ph4[4];
        #pragma unroll
        for (int q = 0; q < 4; q++) ph4[q] = ((const float4*)(part_h + base))[q];
        const float* ph = (const float*)&ph4[0];
        float S = part_s[(size_t)(b * NC + c) * DI + d];
        #pragma unroll
        for (int q = 0; q < 4; q++)
            ((float4*)(part_h + base))[q] = make_float4(h[q*4], h[q*4+1], h[q*4+2], h[q*4+3]);
        #pragma unroll
        for (int s = 0; s < DSN; s++)
            h[s] = fmaf(__expf(A[s] * S), h[s], ph[s]);
    }
}

// pass 3: rescan chunk from h_in, emit gated output to bf16 buffer.
__global__ __launch_bounds__(256) void scan_part2(
    const unsigned short* __restrict__ delta, const unsigned short* __restrict__ xc,
    const float* __restrict__ bc, const unsigned short* __restrict__ xz,
    const float* __restrict__ A_log, const float* __restrict__ Dv,
    const float* __restrict__ part_h,
    unsigned short* __restrict__ out, int L, int CH)
{
    int tid = threadIdx.x;
    int dblk = blockIdx.x & 3;
    int c    = (blockIdx.x >> 2) & (NC - 1);
    int b    = blockIdx.x >> 7;
    int d    = dblk * 256 + tid;
    float A[DSN];
    #pragma unroll
    for (int s = 0; s < DSN; s++) A[s] = -__expf(A_log[d * DSN + s]);
    float Dvd = Dv[d];
    size_t base = ((size_t)(b * NC + c) * DI + d) * DSN;
    float h4[4][4];
    #pragma unroll
    for (int q = 0; q < 4; q++) *((float4*)h4[q]) = ((const float4*)(part_h + base))[q];
    float h[DSN];
    #pragma unroll
    for (int s = 0; s < DSN; s++) h[s] = h4[s >> 2][s & 3];
    int l0 = c * CH;
    for (int l = l0; l < l0 + CH; l++) {
        size_t r = (size_t)b * L + l;
        float4 bq[8];
        const float4* bp = (const float4*)(bc + r * 32);
        #pragma unroll
        for (int q = 0; q < 8; q++) bq[q] = bp[q];
        const float* Bm = (const float*)&bq[0];
        const float* Cm = Bm + DSN;
        float dl = b2f(delta[r * DI + d]);
        float u  = b2f(xc[r * DI + d]);
        float du = dl * u;
        float y = 0.f;
        #pragma unroll
        for (int s = 0; s < DSN; s++) {
            h[s] = fmaf(__expf(dl * A[s]), h[s], du * Bm[s]);
            y = fmaf(h[s], Cm[s], y);
        }
        float z = b2f(xz[r * 2048 + DI + d]);
        float sil = z / (1.f + __expf(-z));
        out[r * DI + d] = f2b((y + u * Dvd) * sil);
    }
}

// ================= residual add + LayerNorm; optional fp32 and bf16 outputs
__global__ __launch_bounds__(128) void addln_kernel(
    const float* __restrict__ a, int amb, int absd, int aro, int lda,
    const float* __restrict__ bsrc,
    const float* __restrict__ g, const float* __restrict__ be,
    float* __restrict__ outf, int omb, int obsd, int oro, int ldo,
    unsigned short* __restrict__ outb, int bmb, int bbsd, int bro, int ldb)
{
    int m = blockIdx.x, t = threadIdx.x;
    int ar = map_row(m, amb, absd, aro);
    float4 x4 = ((const float4*)(a + (size_t)ar * lda))[t];
    float4 y4 = ((const float4*)(bsrc + (size_t)m * DM))[t];
    float v[4] = {x4.x + y4.x, x4.y + y4.y, x4.z + y4.z, x4.w + y4.w};
    float sum = v[0] + v[1] + v[2] + v[3];
    float sq  = v[0]*v[0] + v[1]*v[1] + v[2]*v[2] + v[3]*v[3];
    #pragma unroll
    for (int o = 32; o > 0; o >>= 1) {
        sum += __shfl_down(sum, o);
        sq  += __shfl_down(sq, o);
    }
    __shared__ float s0[2], s1[2];
    if ((t & 63) == 0) { s0[t >> 6] = sum; s1[t >> 6] = sq; }
    __syncthreads();
    float tot = s0[0] + s0[1];
    float tsq = s1[0] + s1[1];
    float mu = tot * (1.f / DM);
    float var = tsq * (1.f / DM) - mu * mu;
    float rs = rsqrtf(var + 1e-6f);
    float4 g4 = ((const float4*)g)[t];
    float4 b4 = ((const float4*)be)[t];
    float o0 = (v[0] - mu) * rs * g4.x + b4.x;
    float o1 = (v[1] - mu) * rs * g4.y + b4.y;
    float o2 = (v[2] - mu) * rs * g4.z + b4.z;
    float o3 = (v[3] - mu) * rs * g4.w + b4.w;
    if (outf) {
        int orow = map_row(m, omb, obsd, oro);
        ((float4*)(outf + (size_t)orow * ldo))[t] = make_float4(o0, o1, o2, o3);
    }
    if (outb) {
        int brow = map_row(m, bmb, bbsd, bro);
        ((ushort4*)(outb + (size_t)brow * ldb))[t] =
            make_ushort4(f2b(o0), f2b(o1), f2b(o2), f2b(o3));
    }
}

// ================= fp32 -> bf16 convert (n4 float4 groups)
__global__ void f2b_kernel(const float* __restrict__ in, unsigned short* __restrict__ out, int n4)
{
    int i = blockIdx.x * 256 + threadIdx.x;
    if (i >= n4) return;
    float4 v = ((const float4*)in)[i];
    ((ushort4*)out)[i] = make_ushort4(f2b(v.x), f2b(v.y), f2b(v.z), f2b(v.w));
}

// ================= merged 6-weight fp32 -> bf16 convert (contiguous bf16 output region)
struct W6 { const float* p[6]; };
__global__ void wconv_kernel(W6 w, unsigned short* __restrict__ out)
{
    const int cum[7] = {0, 262144, 524288, 655360, 786432, 1048576, 1310720};
    int i = blockIdx.x * 256 + threadIdx.x;
    if (i >= 1310720) return;
    int seg = 0;
    #pragma unroll
    for (int s = 1; s < 6; s++) seg += (i >= cum[s]);
    float4 v = ((const float4*)w.p[seg])[i - cum[seg]];
    ((ushort4*)out)[i] = make_ushort4(f2b(v.x), f2b(v.y), f2b(v.z), f2b(v.w));
}

// ================= memory(fp32) -> catb(bf16) rows [b*1536 + 0..1023]
__global__ void mem2catb_kernel(const float* __restrict__ mem, unsigned short* __restrict__ catb)
{
    int f = blockIdx.x * blockDim.x + threadIdx.x;
    const int total = BB * TTM * DM / 4;
    if (f >= total) return;
    const int per_b = TTM * DM / 4;
    int b = f / per_b, rem = f - b * per_b;
    float4 v = ((const float4*)mem)[f];
    ((ushort4*)catb)[(size_t)b * (LCAT * DM / 4) + rem] =
        make_ushort4(f2b(v.x), f2b(v.y), f2b(v.z), f2b(v.w));
}

static void run_scan(const unsigned short* dltb, const unsigned short* xcb, const float* bc,
                     const unsigned short* xzb, const float* A_log, const float* Dv,
                     float* part_h, float* part_s, unsigned short* out, int L,
                     hipStream_t stream)
{
    int CH = L / NC;
    int blocks = BB * NC * (DI / 256);
    scan_part1<<<blocks, 256, 0, stream>>>(dltb, xcb, bc, A_log, part_h, part_s, L, CH);
    scan_combine<<<BB * DI / 256, 256, 0, stream>>>(A_log, part_h, part_s);
    scan_part2<<<blocks, 256, 0, stream>>>(dltb, xcb, bc, xzb, A_log, Dv, part_h, out, L, CH);
}

extern "C" void kernel_launch(void* const* d_in, const int* in_sizes, int n_in,
                              void* d_out, int out_size, void* d_ws, size_t ws_size,
                              hipStream_t stream)
{
    const float* tgt       = (const float*)d_in[0];
    const float* memory    = (const float*)d_in[1];
    const float* s_in_w    = (const float*)d_in[2];
    const float* s_conv_w  = (const float*)d_in[3];
    const float* s_conv_b  = (const float*)d_in[4];
    const float* s_xproj_w = (const float*)d_in[5];
    const float* s_dt_w    = (const float*)d_in[6];
    const float* s_dt_b    = (const float*)d_in[7];
    const float* s_A_log   = (const float*)d_in[8];
    const float* s_D_vec   = (const float*)d_in[9];
    const float* s_out_w   = (const float*)d_in[10];
    const float* c_in_w    = (const float*)d_in[11];
    const float* c_conv_w  = (const float*)d_in[12];
    const float* c_conv_b  = (const float*)d_in[13];
    const float* c_xproj_w = (const float*)d_in[14];
    const float* c_dt_w    = (const float*)d_in[15];
    const float* c_dt_b    = (const float*)d_in[16];
    const float* c_A_log   = (const float*)d_in[17];
    const float* c_D_vec   = (const float*)d_in[18];
    const float* c_out_w   = (const float*)d_in[19];
    const float* ln1_g     = (const float*)d_in[20];
    const float* ln1_b     = (const float*)d_in[21];
    const float* ln2_g     = (const float*)d_in[22];
    const float* ln2_b     = (const float*)d_in[23];
    const float* ln3_g     = (const float*)d_in[24];
    const float* ln3_b     = (const float*)d_in[25];
    const float* ffn_w1    = (const float*)d_in[26];
    const float* ffn_b1    = (const float*)d_in[27];
    const float* ffn_w2    = (const float*)d_in[28];
    const float* ffn_b2    = (const float*)d_in[29];
    float* outp = (float*)d_out;

    // ---- workspace layout ----
    // fp32 region (floats): 11,141,120 floats = 44.6 MB
    float* ws     = (float*)d_ws;
    float* bc     = ws;                     // 393216  (12288 x 32: B|C)
    float* proj   = bc     + 393216;        // 2097152
    float* t1     = proj   + 2097152;       // 2097152
    float* tbuf   = t1     + 2097152;       // 2097152
    float* part_h = tbuf   + 2097152;       // 4194304
    float* part_s = part_h + 4194304;       // 262144
    // bf16 region (ushorts): 81,002,496 elems = 162 MB ; total ~207 MB
    unsigned short* ub      = (unsigned short*)(part_s + 262144);
    unsigned short* dltb    = ub;                   // 12582912 (bf16 delta; ffnout aliases)
    unsigned short* catb    = dltb    + 12582912;   // 6291456
    unsigned short* tgtb    = catb    + 6291456;    // 2097152
    unsigned short* xzb     = tgtb    + 2097152;    // 25165824 (also fbuf alias)
    unsigned short* xcb     = xzb     + 25165824;   // 12582912
    unsigned short* ygb     = xcb     + 12582912;   // 12582912
    unsigned short* tbbf    = ygb     + 12582912;   // 2097152
    unsigned short* s_in_wb = tbbf    + 2097152;    // 1048576  (6-weight block, contiguous)
    unsigned short* c_in_wb = s_in_wb + 1048576;    // 1048576
    unsigned short* s_out_wb= c_in_wb + 1048576;    // 524288
    unsigned short* c_out_wb= s_out_wb+ 524288;     // 524288
    unsigned short* w1b     = c_out_wb+ 524288;     // 1048576
    unsigned short* w2b     = w1b     + 1048576;    // 1048576
    unsigned short* wcomb_s = w2b     + 1048576;    // 1179648 (1152 x 1024)
    unsigned short* wcomb_c = wcomb_s + 1179648;    // 1179648
    unsigned short* fbuf    = xzb;                  // FFN hidden alias
    float* ffnout = (float*)dltb;                   // alias (dltb dead after cross scan)

    // ---- converts & combined-weight fills ----
    f2b_kernel<<<(2097152/4 + 255)/256, 256, 0, stream>>>(tgt, tgtb, 2097152/4);
    mem2catb_kernel<<<(BB*TTM*DM/4 + 255)/256, 256, 0, stream>>>(memory, catb);
    {
        W6 w; w.p[0]=s_in_w; w.p[1]=c_in_w; w.p[2]=s_out_w; w.p[3]=c_out_w; w.p[4]=ffn_w1; w.p[5]=ffn_w2;
        wconv_kernel<<<(1310720 + 255)/256, 256, 0, stream>>>(w, s_in_wb);
    }
    wcomb_kernel<<<(1152*1024)/256, 256, 0, stream>>>(s_dt_w, s_xproj_w, wcomb_s);
    wcomb_kernel<<<(1152*1024)/256, 256, 0, stream>>>(c_dt_w, c_xproj_w, wcomb_c);

    // ---- self mamba (L=512, M=4096) ----
    mgemm_kernel<<<dim3(2048/128, 4096/128), 256, 0, stream>>>(
        tgtb, 4096, 0, 0, s_in_wb, nullptr, nullptr, xzb, nullptr, 2048, 512, ACT_NONE);
    conv_silu_kernel<<<(BB*SS*DI/8 + 255)/256, 256, 0, stream>>>(xzb, s_conv_w, s_conv_b, xcb, SS, BB*SS*DI/8);
    // combined delta + BC GEMM: M=4096, Ncomb=1152, K=1024
    mgemm_kernel<<<dim3(1152/128, 4096/128), 256, 0, stream>>>(
        xcb, 4096, 0, 0, wcomb_s, s_dt_b, nullptr, dltb, bc, 1152, 1024, ACT_DELTA);
    run_scan(dltb, xcb, bc, xzb, s_A_log, s_D_vec, part_h, part_s, ygb, SS, stream);
    mgemm_kernel<<<dim3(512/128, 4096/128), 256, 0, stream>>>(
        ygb, 4096, 0, 0, s_out_wb, nullptr, proj, nullptr, nullptr, 512, 1024, ACT_NONE);
    // t = LN(tgt + proj): fp32 -> t1, bf16 -> catb rows [b*1536+1024+l]
    addln_kernel<<<4096, 128, 0, stream>>>(
        tgt, 4096, 0, 0, DM, proj, ln1_g, ln1_b,
        t1, 4096, 0, 0, DM, catb, 512, 1536, 1024, DM);

    // ---- cross mamba (L=1536, M=12288) ----
    mgemm_kernel<<<dim3(2048/128, 12288/128), 256, 0, stream>>>(
        catb, 12288, 0, 0, c_in_wb, nullptr, nullptr, xzb, nullptr, 2048, 512, ACT_NONE);
    conv_silu_kernel<<<(BB*LCAT*DI/8 + 255)/256, 256, 0, stream>>>(xzb, c_conv_w, c_conv_b, xcb, LCAT, BB*LCAT*DI/8);
    mgemm_kernel<<<dim3(1152/128, 12288/128), 256, 0, stream>>>(
        xcb, 12288, 0, 0, wcomb_c, c_dt_b, nullptr, dltb, bc, 1152, 1024, ACT_DELTA);
    run_scan(dltb, xcb, bc, xzb, c_A_log, c_D_vec, part_h, part_s, ygb, LCAT, stream);
    // out proj over last S rows per batch: row(m) = (m/512)*1536 + 1024 + m%512
    mgemm_kernel<<<dim3(512/128, 4096/128), 256, 0, stream>>>(
        ygb, 512, 1536, 1024, c_out_wb, nullptr, proj, nullptr, nullptr, 512, 1024, ACT_NONE);
    addln_kernel<<<4096, 128, 0, stream>>>(
        t1, 4096, 0, 0, DM, proj, ln2_g, ln2_b,
        tbuf, 4096, 0, 0, DM, tbbf, 4096, 0, 0, DM);

    // ---- FFN ----
    mgemm_kernel<<<dim3(2048/128, 4096/128), 256, 0, stream>>>(
        tbbf, 4096, 0, 0, w1b, ffn_b1, nullptr, fbuf, nullptr, 2048, 512, ACT_RELU);
    mgemm_kernel<<<dim3(512/128, 4096/128), 256, 0, stream>>>(
        fbuf, 4096, 0, 0, w2b, ffn_b2, ffnout, nullptr, nullptr, 512, 2048, ACT_NONE);
    addln_kernel<<<4096, 128, 0, stream>>>(
        tbuf, 4096, 0, 0, DM, ffnout, ln3_g, ln3_b,
        outp, 4096, 0, 0, DM, nullptr, 0, 0, 0, 0);
}

// Round 11
// 663.895 us; speedup vs baseline: 1.2281x; 1.0334x over previous
//
#include <hip/hip_runtime.h>
#include <math.h>

// Problem constants
#define DM    512
#define DI    1024
#define DSN   16
#define DTR   32
#define DFFN  2048
#define BB    8
#define SS    512
#define TTM   1024
#define LCAT  1536
#define NC    32      // scan chunks per sequence

#define ACT_NONE     0
#define ACT_RELU     1
#define ACT_DELTA    3   // split epilogue: n<1024 softplus+bias -> Cb(delta bf16); 1024<=n<1056 -> C2(bc fp32)

typedef __attribute__((ext_vector_type(8))) short short8;
typedef __attribute__((ext_vector_type(8))) unsigned short ushort8;
typedef __attribute__((ext_vector_type(4))) float f32x4;

__device__ __forceinline__ unsigned short f2b(float f) {
    unsigned int u = __float_as_uint(f);
    return (unsigned short)((u + 0x7FFFu + ((u >> 16) & 1u)) >> 16);
}
__device__ __forceinline__ float b2f(unsigned short h) {
    return __uint_as_float(((unsigned int)h) << 16);
}
__device__ __forceinline__ float fast_softplus(float v) {
    return (v > 20.f) ? v : __logf(1.f + __expf(v));
}
__device__ __forceinline__ void gld16(const void* g, void* l) {
    __builtin_amdgcn_global_load_lds(
        (const __attribute__((address_space(1))) void*)g,
        (__attribute__((address_space(3))) void*)l, 16, 0, 0);
}

__device__ __forceinline__ int map_row(int m, int mb, int bs, int ro) {
    int q = m / mb;
    return q * bs + ro + (m - q * mb);
}

// ================= bf16 MFMA GEMM: C[m,n] = act(A[row(m),k] * W[n,k] + bias[n])
// Tile 128x128, BK=64. Row stride = 8 chunks = 128B = full bank wrap, so the
// swizzle must be 3-bit and row-dependent: chunk (row r, k-group g in 0..7)
// lives at position p = r*8 + (g ^ (r&7)).
//  - staging: lane L writes pos c = base+L; r=c>>3, q=c&7, g=q^(r&7). A quad's
//    q is a 4-aligned block; q^(r&7) maps it to another 4-aligned block ->
//    64B contiguous global read per quad -> coalesced.
//  - fragment read: chunk (h*4+fg) of row R is at phase ((h*4)^(fm&4)) +
//    (fg^(fm&3)); over each 16-lane group this covers all 8 bank-quads exactly
//    twice -> conflict-free (R8's validated zero-conflict pattern).
// Optional split-K via gridDim.z==2: z=1 half writes partials to Cf2, no bias.
__global__ __launch_bounds__(256) void mgemm_kernel(
    const unsigned short* __restrict__ A, int mb, int bs, int ro,
    const unsigned short* __restrict__ W, const float* __restrict__ bias,
    float* __restrict__ Cf, unsigned short* __restrict__ Cb,
    float* __restrict__ C2, float* __restrict__ Cf2,
    int N, int K, int act)
{
    __shared__ __align__(16) unsigned short As[128 * 64];
    __shared__ __align__(16) unsigned short Bs[128 * 64];
    int tid = threadIdx.x;
    int lane = tid & 63, wave = tid >> 6;
    int wy = wave >> 1, wx = wave & 1;
    // XCD-band swizzle over (x,y); z (split-K) reuses the same mapping
    int nx = gridDim.x;
    int f = blockIdx.y * nx + blockIdx.x;
    int xcd = f & 7, j2 = f >> 3;
    int bandh = gridDim.y >> 3;
    int m0 = (xcd * bandh + j2 / nx) * 128;
    int n0 = (j2 % nx) * 128;
    // split-K
    int Kh = K / gridDim.z;
    int kbeg = blockIdx.z * Kh, kend = kbeg + Kh;
    float* Cfo = Cf;
    const float* biaso = bias;
    if (blockIdx.z) { Cfo = Cf2; biaso = nullptr; }

    // staging: wave stages chunk positions c = wave*256 + j*64 + lane (j=0..3)
    const unsigned short* ga[4];
    const unsigned short* gb[4];
    unsigned short* la[4];
    unsigned short* lb[4];
    #pragma unroll
    for (int j = 0; j < 4; j++) {
        int c  = wave * 256 + j * 64 + lane;
        int r  = c >> 3;                    // tile row 0..127
        int q  = c & 7;
        int g  = q ^ (r & 7);               // un-swizzled k-chunk 0..7
        int arow = map_row(m0 + r, mb, bs, ro);
        ga[j] = A + (size_t)arow * K + g * 8;
        gb[j] = W + (size_t)(n0 + r) * K + g * 8;
        la[j] = As + (size_t)(wave * 256 + j * 64) * 8;   // chunk pos * 8 shorts
        lb[j] = Bs + (size_t)(wave * 256 + j * 64) * 8;
    }
    // fragment read bases for h=0 and h=1 (R&7 == fm&7: wy*64, t*16 are mult of 8)
    int fm = lane & 15, fg = lane >> 4;
    int swlo = fg ^ (fm & 3);
    int s0 = (fm & 4) + swlo;          // h=0: (0 ^ (fm&4)) + swlo
    int s1 = (4 - (fm & 4)) + swlo;    // h=1: (4 ^ (fm&4)) + swlo
    const unsigned short* arp0 = As + ((size_t)(wy * 64 + fm) * 8 + s0) * 8;
    const unsigned short* arp1 = As + ((size_t)(wy * 64 + fm) * 8 + s1) * 8;
    const unsigned short* brp0 = Bs + ((size_t)(wx * 64 + fm) * 8 + s0) * 8;
    const unsigned short* brp1 = Bs + ((size_t)(wx * 64 + fm) * 8 + s1) * 8;

    f32x4 acc[4][4];
    #pragma unroll
    for (int i = 0; i < 4; i++)
        #pragma unroll
        for (int j = 0; j < 4; j++) acc[i][j] = 0.f;

    for (int k0 = kbeg; k0 < kend; k0 += 64) {
        #pragma unroll
        for (int j = 0; j < 4; j++) {
            gld16(ga[j] + k0, la[j]);
            gld16(gb[j] + k0, lb[j]);
        }
        __syncthreads();
        #pragma unroll
        for (int h = 0; h < 2; h++) {
            const unsigned short* ar = h ? arp1 : arp0;
            const unsigned short* br = h ? brp1 : brp0;
            short8 af[4], bfr[4];
            #pragma unroll
            for (int t = 0; t < 4; t++) af[t]  = *(const short8*)(ar + t * 1024);
            #pragma unroll
            for (int t = 0; t < 4; t++) bfr[t] = *(const short8*)(br + t * 1024);
            #pragma unroll
            for (int i = 0; i < 4; i++)
                #pragma unroll
                for (int j = 0; j < 4; j++)
                    acc[i][j] = __builtin_amdgcn_mfma_f32_16x16x32_bf16(af[i], bfr[j], acc[i][j], 0, 0, 0);
        }
        __syncthreads();
    }

    // epilogue: C/D layout col=lane&15 (n), row=(lane>>4)*4+reg (m)
    int en = lane & 15, em = (lane >> 4) * 4;
    if (act == ACT_DELTA) {
        #pragma unroll
        for (int j = 0; j < 4; j++) {
            int n = n0 + wx * 64 + j * 16 + en;
            bool is_delta = (n < 1024);
            if (!is_delta && n >= 1056) continue;
            float bv = is_delta ? bias[n] : 0.f;
            #pragma unroll
            for (int i = 0; i < 4; i++) {
                int mbase = m0 + wy * 64 + i * 16 + em;
                #pragma unroll
                for (int r = 0; r < 4; r++) {
                    float v = acc[i][j][r] + bv;
                    if (is_delta) {
                        Cb[(size_t)(mbase + r) * 1024 + n] = f2b(fast_softplus(v));
                    } else {
                        C2[(size_t)(mbase + r) * 32 + (n - 1024)] = v;
                    }
                }
            }
        }
        return;
    }
    #pragma unroll
    for (int j = 0; j < 4; j++) {
        int n = n0 + wx * 64 + j * 16 + en;
        float bv = biaso ? biaso[n] : 0.f;
        #pragma unroll
        for (int i = 0; i < 4; i++) {
            int mbase = m0 + wy * 64 + i * 16 + em;
            #pragma unroll
            for (int r = 0; r < 4; r++) {
                float v = acc[i][j][r] + bv;
                if (act == ACT_RELU) v = v > 0.f ? v : 0.f;
                size_t off = (size_t)(mbase + r) * N + n;
                if (Cb) Cb[off] = f2b(v);
                else    Cfo[off] = v;
            }
        }
    }
}

// ================= Wcomb fill: rows 0..1023 = dt_w @ xproj[:32]; 1024..1055 = xproj rows 32..63; rest 0
__global__ void wcomb_kernel(const float* __restrict__ dt_w,
                             const float* __restrict__ xproj,
                             unsigned short* __restrict__ out)
{
    int idx = blockIdx.x * 256 + threadIdx.x;   // n*1024 + k, n < 1152
    int n = idx >> 10, k = idx & 1023;
    float v = 0.f;
    if (n < 1024) {
        #pragma unroll
        for (int r = 0; r < DTR; r++)
            v = fmaf(dt_w[n * DTR + r], xproj[r * 1024 + k], v);
    } else if (n < 1056) {
        v = xproj[(n - 1024 + 32) * 1024 + k];
    }
    out[idx] = f2b(v);
}

// ================= Depthwise causal conv (width 4) + bias + SiLU.
// Vectorized: one thread per 8 consecutive channels (ushort8 = 16B/lane).
__global__ __launch_bounds__(256) void conv_silu_kernel(
    const unsigned short* __restrict__ xz,
    const float* __restrict__ cw,
    const float* __restrict__ cb,
    unsigned short* __restrict__ xc, int L, int total8)
{
    int idx = blockIdx.x * blockDim.x + threadIdx.x;
    if (idx >= total8) return;
    int d8 = idx & 127;            // channel group (1024/8 = 128 per row)
    int d0 = d8 * 8;
    int r  = idx >> 7;             // b*L + l
    int l  = r % L;
    float acc[8];
    {
        float4 c0 = ((const float4*)(cb + d0))[0];
        float4 c1 = ((const float4*)(cb + d0))[1];
        acc[0]=c0.x; acc[1]=c0.y; acc[2]=c0.z; acc[3]=c0.w;
        acc[4]=c1.x; acc[5]=c1.y; acc[6]=c1.z; acc[7]=c1.w;
    }
    float4 wv[8];
    #pragma unroll
    for (int j = 0; j < 8; j++) wv[j] = *(const float4*)(cw + (d0 + j) * 4);
    #pragma unroll
    for (int k = 0; k < 4; k++) {
        int ls = l - 3 + k;
        if (ls >= 0) {
            ushort8 v = *(const ushort8*)(xz + (size_t)(r - 3 + k) * 2048 + d0);
            const float* w = (const float*)&wv[0];
            #pragma unroll
            for (int j = 0; j < 8; j++)
                acc[j] = fmaf(b2f(v[j]), w[j * 4 + k], acc[j]);
        }
    }
    ushort8 o;
    #pragma unroll
    for (int j = 0; j < 8; j++) {
        float s = acc[j] / (1.f + __expf(-acc[j]));
        o[j] = f2b(s);
    }
    *(ushort8*)(xc + (size_t)r * 1024 + d0) = o;
}

// ================= Chunked selective scan (delta bf16)
__global__ __launch_bounds__(256) void scan_part1(
    const unsigned short* __restrict__ delta, const unsigned short* __restrict__ xc,
    const float* __restrict__ bc, const float* __restrict__ A_log,
    float* __restrict__ part_h, float* __restrict__ part_s, int L, int CH)
{
    int tid = threadIdx.x;
    int dblk = blockIdx.x & 3;
    int c    = (blockIdx.x >> 2) & (NC - 1);
    int b    = blockIdx.x >> 7;
    int d    = dblk * 256 + tid;
    float A[DSN];
    #pragma unroll
    for (int s = 0; s < DSN; s++) A[s] = -__expf(A_log[d * DSN + s]);
    float h[DSN];
    #pragma unroll
    for (int s = 0; s < DSN; s++) h[s] = 0.f;
    float ssum = 0.f;
    int l0 = c * CH;
    for (int l = l0; l < l0 + CH; l++) {
        size_t r = (size_t)b * L + l;
        float4 bq[4];
        const float4* bp = (const float4*)(bc + r * 32);
        #pragma unroll
        for (int q = 0; q < 4; q++) bq[q] = bp[q];
        const float* Bm = (const float*)&bq[0];
        float dl = b2f(delta[r * DI + d]);
        float u  = b2f(xc[r * DI + d]);
        float du = dl * u;
        ssum += dl;
        #pragma unroll
        for (int s = 0; s < DSN; s++)
            h[s] = fmaf(__expf(dl * A[s]), h[s], du * Bm[s]);
    }
    size_t base = ((size_t)(b * NC + c) * DI + d) * DSN;
    #pragma unroll
    for (int q = 0; q < 4; q++)
        ((float4*)(part_h + base))[q] = make_float4(h[q*4], h[q*4+1], h[q*4+2], h[q*4+3]);
    part_s[(size_t)(b * NC + c) * DI + d] = ssum;
}

__global__ __launch_bounds__(256) void scan_combine(
    const float* __restrict__ A_log,
    float* __restrict__ part_h, const float* __restrict__ part_s)
{
    int idx = blockIdx.x * 256 + threadIdx.x;
    int b = idx >> 10, d = idx & (DI - 1);
    float A[DSN];
    #pragma unroll
    for (int s = 0; s < DSN; s++) A[s] = -__expf(A_log[d * DSN + s]);
    float h[DSN];
    #pragma unroll
    for (int s = 0; s < DSN; s++) h[s] = 0.f;
    for (int c = 0; c < NC; c++) {
        size_t base = ((size_t)(b * NC + c) * DI + d) * DSN;
        float4 ph4[4];
        #pragma unroll
        for (int q = 0; q < 4; q++) ph4[q] = ((const float4*)(part_h + base))[q];
        const float* ph = (const float*)&ph4[0];
        float S = part_s[(size_t)(b * NC + c) * DI + d];
        #pragma unroll
        for (int q = 0; q < 4; q++)
            ((float4*)(part_h + base))[q] = make_float4(h[q*4], h[q*4+1], h[q*4+2], h[q*4+3]);
        #pragma unroll
        for (int s = 0; s < DSN; s++)
            h[s] = fmaf(__expf(A[s] * S), h[s], ph[s]);
    }
}

// pass 3: rescan chunk from h_in, emit gated output to bf16 buffer.
__global__ __launch_bounds__(256) void scan_part2(
    const unsigned short* __restrict__ delta, const unsigned short* __restrict__ xc,
    const float* __restrict__ bc, const unsigned short* __restrict__ xz,
    const float* __restrict__ A_log, const float* __restrict__ Dv,
    const float* __restrict__ part_h,
    unsigned short* __restrict__ out, int L, int CH)
{
    int tid = threadIdx.x;
    int dblk = blockIdx.x & 3;
    int c    = (blockIdx.x >> 2) & (NC - 1);
    int b    = blockIdx.x >> 7;
    int d    = dblk * 256 + tid;
    float A[DSN];
    #pragma unroll
    for (int s = 0; s < DSN; s++) A[s] = -__expf(A_log[d * DSN + s]);
    float Dvd = Dv[d];
    size_t base = ((size_t)(b * NC + c) * DI + d) * DSN;
    float h4[4][4];
    #pragma unroll
    for (int q = 0; q < 4; q++) *((float4*)h4[q]) = ((const float4*)(part_h + base))[q];
    float h[DSN];
    #pragma unroll
    for (int s = 0; s < DSN; s++) h[s] = h4[s >> 2][s & 3];
    int l0 = c * CH;
    for (int l = l0; l < l0 + CH; l++) {
        size_t r = (size_t)b * L + l;
        float4 bq[8];
        const float4* bp = (const float4*)(bc + r * 32);
        #pragma unroll
        for (int q = 0; q < 8; q++) bq[q] = bp[q];
        const float* Bm = (const float*)&bq[0];
        const float* Cm = Bm + DSN;
        float dl = b2f(delta[r * DI + d]);
        float u  = b2f(xc[r * DI + d]);
        float du = dl * u;
        float y = 0.f;
        #pragma unroll
        for (int s = 0; s < DSN; s++) {
            h[s] = fmaf(__expf(dl * A[s]), h[s], du * Bm[s]);
            y = fmaf(h[s], Cm[s], y);
        }
        float z = b2f(xz[r * 2048 + DI + d]);
        float sil = z / (1.f + __expf(-z));
        out[r * DI + d] = f2b((y + u * Dvd) * sil);
    }
}

// ================= residual add + LayerNorm; a + bsrc (+ bsrc2); fp32/bf16 outs
__global__ __launch_bounds__(128) void addln_kernel(
    const float* __restrict__ a, int amb, int absd, int aro, int lda,
    const float* __restrict__ bsrc, const float* __restrict__ bsrc2,
    const float* __restrict__ g, const float* __restrict__ be,
    float* __restrict__ outf, int omb, int obsd, int oro, int ldo,
    unsigned short* __restrict__ outb, int bmb, int bbsd, int bro, int ldb)
{
    int m = blockIdx.x, t = threadIdx.x;
    int ar = map_row(m, amb, absd, aro);
    float4 x4 = ((const float4*)(a + (size_t)ar * lda))[t];
    float4 y4 = ((const float4*)(bsrc + (size_t)m * DM))[t];
    float v[4] = {x4.x + y4.x, x4.y + y4.y, x4.z + y4.z, x4.w + y4.w};
    if (bsrc2) {
        float4 z4 = ((const float4*)(bsrc2 + (size_t)m * DM))[t];
        v[0] += z4.x; v[1] += z4.y; v[2] += z4.z; v[3] += z4.w;
    }
    float sum = v[0] + v[1] + v[2] + v[3];
    float sq  = v[0]*v[0] + v[1]*v[1] + v[2]*v[2] + v[3]*v[3];
    #pragma unroll
    for (int o = 32; o > 0; o >>= 1) {
        sum += __shfl_down(sum, o);
        sq  += __shfl_down(sq, o);
    }
    __shared__ float s0[2], s1[2];
    if ((t & 63) == 0) { s0[t >> 6] = sum; s1[t >> 6] = sq; }
    __syncthreads();
    float tot = s0[0] + s0[1];
    float tsq = s1[0] + s1[1];
    float mu = tot * (1.f / DM);
    float var = tsq * (1.f / DM) - mu * mu;
    float rs = rsqrtf(var + 1e-6f);
    float4 g4 = ((const float4*)g)[t];
    float4 b4 = ((const float4*)be)[t];
    float o0 = (v[0] - mu) * rs * g4.x + b4.x;
    float o1 = (v[1] - mu) * rs * g4.y + b4.y;
    float o2 = (v[2] - mu) * rs * g4.z + b4.z;
    float o3 = (v[3] - mu) * rs * g4.w + b4.w;
    if (outf) {
        int orow = map_row(m, omb, obsd, oro);
        ((float4*)(outf + (size_t)orow * ldo))[t] = make_float4(o0, o1, o2, o3);
    }
    if (outb) {
        int brow = map_row(m, bmb, bbsd, bro);
        ((ushort4*)(outb + (size_t)brow * ldb))[t] =
            make_ushort4(f2b(o0), f2b(o1), f2b(o2), f2b(o3));
    }
}

// ================= fp32 -> bf16 convert (n4 float4 groups)
__global__ void f2b_kernel(const float* __restrict__ in, unsigned short* __restrict__ out, int n4)
{
    int i = blockIdx.x * 256 + threadIdx.x;
    if (i >= n4) return;
    float4 v = ((const float4*)in)[i];
    ((ushort4*)out)[i] = make_ushort4(f2b(v.x), f2b(v.y), f2b(v.z), f2b(v.w));
}

// ================= merged 6-weight fp32 -> bf16 convert (contiguous bf16 output region)
struct W6 { const float* p[6]; };
__global__ void wconv_kernel(W6 w, unsigned short* __restrict__ out)
{
    const int cum[7] = {0, 262144, 524288, 655360, 786432, 1048576, 1310720};
    int i = blockIdx.x * 256 + threadIdx.x;
    if (i >= 1310720) return;
    int seg = 0;
    #pragma unroll
    for (int s = 1; s < 6; s++) seg += (i >= cum[s]);
    float4 v = ((const float4*)w.p[seg])[i - cum[seg]];
    ((ushort4*)out)[i] = make_ushort4(f2b(v.x), f2b(v.y), f2b(v.z), f2b(v.w));
}

// ================= memory(fp32) -> catb(bf16) rows [b*1536 + 0..1023]
__global__ void mem2catb_kernel(const float* __restrict__ mem, unsigned short* __restrict__ catb)
{
    int f = blockIdx.x * blockDim.x + threadIdx.x;
    const int total = BB * TTM * DM / 4;
    if (f >= total) return;
    const int per_b = TTM * DM / 4;
    int b = f / per_b, rem = f - b * per_b;
    float4 v = ((const float4*)mem)[f];
    ((ushort4*)catb)[(size_t)b * (LCAT * DM / 4) + rem] =
        make_ushort4(f2b(v.x), f2b(v.y), f2b(v.z), f2b(v.w));
}

static void run_scan(const unsigned short* dltb, const unsigned short* xcb, const float* bc,
                     const unsigned short* xzb, const float* A_log, const float* Dv,
                     float* part_h, float* part_s, unsigned short* out, int L,
                     hipStream_t stream)
{
    int CH = L / NC;
    int blocks = BB * NC * (DI / 256);
    scan_part1<<<blocks, 256, 0, stream>>>(dltb, xcb, bc, A_log, part_h, part_s, L, CH);
    scan_combine<<<BB * DI / 256, 256, 0, stream>>>(A_log, part_h, part_s);
    scan_part2<<<blocks, 256, 0, stream>>>(dltb, xcb, bc, xzb, A_log, Dv, part_h, out, L, CH);
}

extern "C" void kernel_launch(void* const* d_in, const int* in_sizes, int n_in,
                              void* d_out, int out_size, void* d_ws, size_t ws_size,
                              hipStream_t stream)
{
    const float* tgt       = (const float*)d_in[0];
    const float* memory    = (const float*)d_in[1];
    const float* s_in_w    = (const float*)d_in[2];
    const float* s_conv_w  = (const float*)d_in[3];
    const float* s_conv_b  = (const float*)d_in[4];
    const float* s_xproj_w = (const float*)d_in[5];
    const float* s_dt_w    = (const float*)d_in[6];
    const float* s_dt_b    = (const float*)d_in[7];
    const float* s_A_log   = (const float*)d_in[8];
    const float* s_D_vec   = (const float*)d_in[9];
    const float* s_out_w   = (const float*)d_in[10];
    const float* c_in_w    = (const float*)d_in[11];
    const float* c_conv_w  = (const float*)d_in[12];
    const float* c_conv_b  = (const float*)d_in[13];
    const float* c_xproj_w = (const float*)d_in[14];
    const float* c_dt_w    = (const float*)d_in[15];
    const float* c_dt_b    = (const float*)d_in[16];
    const float* c_A_log   = (const float*)d_in[17];
    const float* c_D_vec   = (const float*)d_in[18];
    const float* c_out_w   = (const float*)d_in[19];
    const float* ln1_g     = (const float*)d_in[20];
    const float* ln1_b     = (const float*)d_in[21];
    const float* ln2_g     = (const float*)d_in[22];
    const float* ln2_b     = (const float*)d_in[23];
    const float* ln3_g     = (const float*)d_in[24];
    const float* ln3_b     = (const float*)d_in[25];
    const float* ffn_w1    = (const float*)d_in[26];
    const float* ffn_b1    = (const float*)d_in[27];
    const float* ffn_w2    = (const float*)d_in[28];
    const float* ffn_b2    = (const float*)d_in[29];
    float* outp = (float*)d_out;

    // ---- workspace layout ----
    // fp32 region (floats): 13,238,272 floats = 53 MB
    float* ws     = (float*)d_ws;
    float* bc     = ws;                     // 393216  (12288 x 32: B|C)
    float* proj   = bc     + 393216;        // 2097152
    float* proj2  = proj   + 2097152;       // 2097152 (split-K partial)
    float* t1     = proj2  + 2097152;       // 2097152
    float* tbuf   = t1     + 2097152;       // 2097152
    float* part_h = tbuf   + 2097152;       // 4194304
    float* part_s = part_h + 4194304;       // 262144
    // bf16 region (ushorts): 81,002,496 elems = 162 MB ; total ~215 MB
    unsigned short* ub      = (unsigned short*)(part_s + 262144);
    unsigned short* dltb    = ub;                   // 12582912 (bf16 delta; ffnout aliases)
    unsigned short* catb    = dltb    + 12582912;   // 6291456
    unsigned short* tgtb    = catb    + 6291456;    // 2097152
    unsigned short* xzb     = tgtb    + 2097152;    // 25165824 (also fbuf alias)
    unsigned short* xcb     = xzb     + 25165824;   // 12582912
    unsigned short* ygb     = xcb     + 12582912;   // 12582912
    unsigned short* tbbf    = ygb     + 12582912;   // 2097152
    unsigned short* s_in_wb = tbbf    + 2097152;    // 1048576  (6-weight block, contiguous)
    unsigned short* c_in_wb = s_in_wb + 1048576;    // 1048576
    unsigned short* s_out_wb= c_in_wb + 1048576;    // 524288
    unsigned short* c_out_wb= s_out_wb+ 524288;     // 524288
    unsigned short* w1b     = c_out_wb+ 524288;     // 1048576
    unsigned short* w2b     = w1b     + 1048576;    // 1048576
    unsigned short* wcomb_s = w2b     + 1048576;    // 1179648 (1152 x 1024)
    unsigned short* wcomb_c = wcomb_s + 1179648;    // 1179648
    unsigned short* fbuf    = xzb;                  // FFN hidden alias
    float* ffnout  = (float*)dltb;                  // alias (dltb dead after cross scan)
    float* ffnout2 = ffnout + 2097152;              // split-K partial (fits in dltb region)

    // ---- converts & combined-weight fills ----
    f2b_kernel<<<(2097152/4 + 255)/256, 256, 0, stream>>>(tgt, tgtb, 2097152/4);
    mem2catb_kernel<<<(BB*TTM*DM/4 + 255)/256, 256, 0, stream>>>(memory, catb);
    {
        W6 w; w.p[0]=s_in_w; w.p[1]=c_in_w; w.p[2]=s_out_w; w.p[3]=c_out_w; w.p[4]=ffn_w1; w.p[5]=ffn_w2;
        wconv_kernel<<<(1310720 + 255)/256, 256, 0, stream>>>(w, s_in_wb);
    }
    wcomb_kernel<<<(1152*1024)/256, 256, 0, stream>>>(s_dt_w, s_xproj_w, wcomb_s);
    wcomb_kernel<<<(1152*1024)/256, 256, 0, stream>>>(c_dt_w, c_xproj_w, wcomb_c);

    // ---- self mamba (L=512, M=4096) ----
    mgemm_kernel<<<dim3(2048/128, 4096/128), 256, 0, stream>>>(
        tgtb, 4096, 0, 0, s_in_wb, nullptr, nullptr, xzb, nullptr, nullptr, 2048, 512, ACT_NONE);
    conv_silu_kernel<<<(BB*SS*DI/8 + 255)/256, 256, 0, stream>>>(xzb, s_conv_w, s_conv_b, xcb, SS, BB*SS*DI/8);
    // combined delta + BC GEMM: M=4096, Ncomb=1152, K=1024
    mgemm_kernel<<<dim3(1152/128, 4096/128), 256, 0, stream>>>(
        xcb, 4096, 0, 0, wcomb_s, s_dt_b, nullptr, dltb, bc, nullptr, 1152, 1024, ACT_DELTA);
    run_scan(dltb, xcb, bc, xzb, s_A_log, s_D_vec, part_h, part_s, ygb, SS, stream);
    // out-proj: split-K=2 (N=512 -> only 128 blocks otherwise)
    mgemm_kernel<<<dim3(512/128, 4096/128, 2), 256, 0, stream>>>(
        ygb, 4096, 0, 0, s_out_wb, nullptr, proj, nullptr, nullptr, proj2, 512, 1024, ACT_NONE);
    // t = LN(tgt + proj + proj2): fp32 -> t1, bf16 -> catb rows [b*1536+1024+l]
    addln_kernel<<<4096, 128, 0, stream>>>(
        tgt, 4096, 0, 0, DM, proj, proj2, ln1_g, ln1_b,
        t1, 4096, 0, 0, DM, catb, 512, 1536, 1024, DM);

    // ---- cross mamba (L=1536, M=12288) ----
    mgemm_kernel<<<dim3(2048/128, 12288/128), 256, 0, stream>>>(
        catb, 12288, 0, 0, c_in_wb, nullptr, nullptr, xzb, nullptr, nullptr, 2048, 512, ACT_NONE);
    conv_silu_kernel<<<(BB*LCAT*DI/8 + 255)/256, 256, 0, stream>>>(xzb, c_conv_w, c_conv_b, xcb, LCAT, BB*LCAT*DI/8);
    mgemm_kernel<<<dim3(1152/128, 12288/128), 256, 0, stream>>>(
        xcb, 12288, 0, 0, wcomb_c, c_dt_b, nullptr, dltb, bc, nullptr, 1152, 1024, ACT_DELTA);
    run_scan(dltb, xcb, bc, xzb, c_A_log, c_D_vec, part_h, part_s, ygb, LCAT, stream);
    // out proj over last S rows per batch, split-K=2
    mgemm_kernel<<<dim3(512/128, 4096/128, 2), 256, 0, stream>>>(
        ygb, 512, 1536, 1024, c_out_wb, nullptr, proj, nullptr, nullptr, proj2, 512, 1024, ACT_NONE);
    addln_kernel<<<4096, 128, 0, stream>>>(
        t1, 4096, 0, 0, DM, proj, proj2, ln2_g, ln2_b,
        tbuf, 4096, 0, 0, DM, tbbf, 4096, 0, 0, DM);

    // ---- FFN ----
    mgemm_kernel<<<dim3(2048/128, 4096/128), 256, 0, stream>>>(
        tbbf, 4096, 0, 0, w1b, ffn_b1, nullptr, fbuf, nullptr, nullptr, 2048, 512, ACT_RELU);
    // FFN2: split-K=2
    mgemm_kernel<<<dim3(512/128, 4096/128, 2), 256, 0, stream>>>(
        fbuf, 4096, 0, 0, w2b, ffn_b2, ffnout, nullptr, nullptr, ffnout2, 512, 2048, ACT_NONE);
    addln_kernel<<<4096, 128, 0, stream>>>(
        tbuf, 4096, 0, 0, DM, ffnout, ffnout2, ln3_g, ln3_b,
        outp, 4096, 0, 0, DM, nullptr, 0, 0, 0, 0);
}